// Round 8
// baseline (6314.634 us; speedup 1.0000x reference)
//
#include <hip/hip_runtime.h>
#include <cstdint>
#include <cstddef>

typedef __attribute__((ext_vector_type(8))) short short8;
typedef __attribute__((ext_vector_type(4))) float f32x4;
typedef __attribute__((ext_vector_type(4))) unsigned int u32x4;

#define NEG_LOG2E -1.44269504088896340736f
#define MFMA_BF16 __builtin_amdgcn_mfma_f32_16x16x32_bf16

// ---- helpers -------------------------------------------------------------
static __device__ __forceinline__ unsigned int cvt_pk_bf16(float lo, float hi) {
  unsigned int r;
  asm("v_cvt_pk_bf16_f32 %0, %1, %2" : "=v"(r) : "v"(lo), "v"(hi));
  return r;
}
// xs is pre-scaled by -log2(e): returns sigmoid(x_true)
static __device__ __forceinline__ float sigmoid_scaled(float xs) {
  return __builtin_amdgcn_rcpf(1.0f + __builtin_amdgcn_exp2f(xs));
}

// ---- asm MFMA building blocks (NON-volatile dataflow nodes).  ALL outputs
// EARLY-CLOBBER ("+&v"): prevents output regs aliasing inputs inside
// multi-instruction blobs (the r6 NaN).  Hazard discipline is structural:
//   * mfma4_first: leading s_nop 3 covers VALU zero-init -> MFMA SrcC.
//   * mfma4_last: trailing s_nop 7/7/3 (20 cyc) covers MFMA D -> VALU read;
//     every 4-chain group ENDS with mfma4_last, and any VALU consumer is
//     data-dependent on that blob, so the distance holds under ANY
//     scheduler order -- no external fences needed.
static __device__ __forceinline__ f32x4 mfma_ab(short8 a, short8 b, f32x4 c) {
  asm("v_mfma_f32_16x16x32_bf16 %0, %1, %2, %0"
      : "+&v"(c)
      : "v"(a), "a"(b));
  return c;
}
static __device__ __forceinline__ void mfma4_first(short8 a, short8 w0,
                                                   short8 w1, short8 w2,
                                                   short8 w3, f32x4& c0,
                                                   f32x4& c1, f32x4& c2,
                                                   f32x4& c3) {
  asm("s_nop 3\n\t"
      "v_mfma_f32_16x16x32_bf16 %0, %4, %5, %0\n\t"
      "v_mfma_f32_16x16x32_bf16 %1, %4, %6, %1\n\t"
      "v_mfma_f32_16x16x32_bf16 %2, %4, %7, %2\n\t"
      "v_mfma_f32_16x16x32_bf16 %3, %4, %8, %3"
      : "+&v"(c0), "+&v"(c1), "+&v"(c2), "+&v"(c3)
      : "v"(a), "a"(w0), "a"(w1), "a"(w2), "a"(w3));
}
static __device__ __forceinline__ void mfma4_last(short8 a, short8 w0,
                                                  short8 w1, short8 w2,
                                                  short8 w3, f32x4& c0,
                                                  f32x4& c1, f32x4& c2,
                                                  f32x4& c3) {
  asm("v_mfma_f32_16x16x32_bf16 %0, %4, %5, %0\n\t"
      "v_mfma_f32_16x16x32_bf16 %1, %4, %6, %1\n\t"
      "v_mfma_f32_16x16x32_bf16 %2, %4, %7, %2\n\t"
      "v_mfma_f32_16x16x32_bf16 %3, %4, %8, %3\n\t"
      "s_nop 7\n\ts_nop 7\n\ts_nop 3"
      : "+&v"(c0), "+&v"(c1), "+&v"(c2), "+&v"(c3)
      : "v"(a), "a"(w0), "a"(w1), "a"(w2), "a"(w3));
}

// ===========================================================================
// Kernel 1: repack w_rec (fp32 [1024][256]) -> bf16 fragment buffer, scaled
// by -log2(e).  512 frag slots of 1 KB; slot f, lane l, elems e0..7 hold the
// MFMA B-operand fragment: w'[ct*16 + (l&15)][kt*32 + (l>>4)*8 + e].
// Slot layout (w = wave 0..3 of rnn_scan):
//   f = w*64 + q,        q=0..63 : jt = 2w + (q>>5), g=(q>>3)&3, kt=q&7  (AGPR)
//   f = 256 + w*32 + q,  q=0..31 : jt = 2w + 8,      g=q>>3,     kt=q&7  (VGPR)
//   f = 384 + w*32 + q,  q=0..31 : jt = 2w + 9,      g=q>>3,     kt=q&7  (LDS)
// where ct = jt + 16g.
// ===========================================================================
__global__ void wfrag_setup(const float* __restrict__ w_rec,
                            unsigned short* __restrict__ wf) {
  const int f = blockIdx.x;   // 0..511
  const int l = threadIdx.x;  // 0..63
  int jt, g, kt;
  if (f < 256) {
    const int w = f >> 6, q = f & 63;
    jt = 2 * w + (q >> 5); g = (q >> 3) & 3; kt = q & 7;
  } else if (f < 384) {
    const int r = f - 256; const int w = r >> 5, q = r & 31;
    jt = 2 * w + 8; g = q >> 3; kt = q & 7;
  } else {
    const int r = f - 384; const int w = r >> 5, q = r & 31;
    jt = 2 * w + 9; g = q >> 3; kt = q & 7;
  }
  const int ct = jt + 16 * g;
  const float* src = w_rec + (size_t)(ct * 16 + (l & 15)) * 256 + kt * 32 + (l >> 4) * 8;
  u32x4 ov;
#pragma unroll
  for (int e = 0; e < 4; ++e)
    ov[e] = cvt_pk_bf16(src[2 * e] * NEG_LOG2E, src[2 * e + 1] * NEG_LOG2E);
  *(u32x4*)(wf + (size_t)f * 512 + (size_t)l * 8) = ov;
}

// ===========================================================================
// Kernel 2: gx = (x @ w_in^T + b) * -log2(e), written as bf16 packed in the
// EXACT layout the RNN consumes:
//   dword[ ((t*16 + bg)*32 + p)*64 + lane ] = bf16(ct=2p) | bf16(ct=2p+1)<<16
// where for (t, b=bg*4+bl, col): lane = bl*16 + (col&15), p = (col>>4)>>1.
// 128x128 tile, 4 waves, K=256, operands loaded straight from global fp32.
// ===========================================================================
static __device__ __forceinline__ short8 ldcvt8(const float* p) {
  f32x4 v0 = *(const f32x4*)p;
  f32x4 v1 = *(const f32x4*)(p + 4);
  u32x4 u;
  u[0] = cvt_pk_bf16(v0[0], v0[1]);
  u[1] = cvt_pk_bf16(v0[2], v0[3]);
  u[2] = cvt_pk_bf16(v1[0], v1[1]);
  u[3] = cvt_pk_bf16(v1[2], v1[3]);
  return __builtin_bit_cast(short8, u);
}

__global__ __launch_bounds__(256) void gemm_gx(const float* __restrict__ x,
                                               const float* __restrict__ w_in,
                                               const float* __restrict__ bias,
                                               unsigned int* __restrict__ gx) {
  const int l = threadIdx.x & 63, wid = threadIdx.x >> 6;
  const int mq = wid >> 1, nq = wid & 1;
  const int mbase = blockIdx.x * 128 + mq * 64;
  const int nbase = blockIdx.y * 128 + nq * 64;
  const int lr = l & 15;
  const int lk = (l >> 4) * 8;

  f32x4 acc[4][4] = {};
#pragma unroll
  for (int kt = 0; kt < 8; ++kt) {
    const int k0 = kt * 32 + lk;
    short8 af[4], bf[4];
#pragma unroll
    for (int mt = 0; mt < 4; ++mt)
      af[mt] = ldcvt8(x + (size_t)(mbase + mt * 16 + lr) * 256 + k0);
#pragma unroll
    for (int nt = 0; nt < 4; ++nt)
      bf[nt] = ldcvt8(w_in + (size_t)(nbase + nt * 16 + lr) * 256 + k0);
#pragma unroll
    for (int mt = 0; mt < 4; ++mt)
#pragma unroll
      for (int nt = 0; nt < 4; ++nt)
        acc[mt][nt] = MFMA_BF16(af[mt], bf[nt], acc[mt][nt], 0, 0, 0);
  }

  float bv[4];
#pragma unroll
  for (int nt = 0; nt < 4; ++nt) bv[nt] = bias[nbase + nt * 16 + lr];

#pragma unroll
  for (int mt = 0; mt < 4; ++mt) {
    const int m0 = mbase + mt * 16;                 // 16-aligned
    const int tt = m0 >> 6;                         // chunk-local t
    const int bg = ((m0 & 63) >> 2) + (l >> 4);     // = mt*4 + (l>>4)
#pragma unroll
    for (int ntp = 0; ntp < 2; ++ntp) {
      const int p = (nbase >> 5) + ntp;             // ct-pair index 0..31
#pragma unroll
      for (int r = 0; r < 4; ++r) {
        float e0 = (acc[mt][ntp * 2 + 0][r] + bv[ntp * 2 + 0]) * NEG_LOG2E;
        float e1 = (acc[mt][ntp * 2 + 1][r] + bv[ntp * 2 + 1]) * NEG_LOG2E;
        gx[(((size_t)tt * 16 + bg) * 32 + p) * 64 + (r * 16 + lr)] =
            cvt_pk_bf16(e0, e1);
      }
    }
  }
}

// ===========================================================================
// Kernel 3: the sequential scan.  16 blocks (bg = 4 batches each), 4 waves.
// All weights resident per CU:
//   jidx 0,1 -> 64 frags/wave BORN in AGPRs ("=a" global_load, 256 AGPRs)
//   jidx 2   -> 32 frags/wave in arch VGPRs (128 regs, intrinsic path)
//   jidx 3   -> 32 frags/wave in LDS (128 KB total, lane-linear)
// Step order (r8): the OPAQUE asm region runs FIRST (64 AGPR MFMAs; af
// ds_reads + gx prefetch pipeline into it), then the 64 INTRINSIC MFMAs with
// EPI(0)/EPI(1)/EPI(2) placed in the same region -- everything there is
// intrinsic/VALU, which the MI scheduler can weave (it knows MFMA latency).
// No mid-step fences: each asm group ends in mfma4_last (20-cyc nop tail),
// and EPI reads are data-dependent on those blobs.  One raw s_barrier per
// step with LDS-only drain; gx prefetch + out stores stay in flight.
// ===========================================================================
#define HB_ROW 544                      // 512B data + 32B pad (bank spread)
#define HB_SZ (4 * HB_ROW)              // 2176
#define LDSW_SZ (128 * 1024)
#define LDS_TOTAL (LDSW_SZ + 2 * HB_SZ) // 135424

// 4 weight-frag loads straight into AGPRs.  Outputs are AGPR-class from
// birth -> later "a" MFMA operands need no copies.
#define LD4A(i)                                                         \
  asm volatile("global_load_dwordx4 %0, %4, off\n\t"                    \
               "global_load_dwordx4 %1, %4, off offset:1024\n\t"        \
               "global_load_dwordx4 %2, %4, off offset:2048\n\t"        \
               "global_load_dwordx4 %3, %4, off offset:3072"            \
               : "=&a"(wa[4 * (i)]), "=&a"(wa[4 * (i) + 1]),            \
                 "=&a"(wa[4 * (i) + 2]), "=&a"(wa[4 * (i) + 3])         \
               : "v"(pA + 4096 * (i)))

__global__ __launch_bounds__(256, 1) void rnn_scan(
    const unsigned short* __restrict__ wf, const unsigned int* __restrict__ gx,
    float* __restrict__ out, float* __restrict__ hstate,
    float* __restrict__ cstate, int first) {
  extern __shared__ char lds[];
  char* ldsW = lds;
  char* hb0 = lds + LDSW_SZ;
  char* hb1 = hb0 + HB_SZ;

  const int l = threadIdx.x & 63;
  const int w = threadIdx.x >> 6;
  const int bg = blockIdx.x;      // 0..15 -> batches 4bg..4bg+3
  const int bloc = l >> 4;        // local batch 0..3
  const int col = l & 15;
  const int jts[4] = {2 * w, 2 * w + 1, 2 * w + 8, 2 * w + 9};

  // ---- prologue: weights jidx 0,1 -> AGPRs (64 frags, contiguous region) --
  short8 wa[64];
  {
    const char* pA = (const char*)wf + (size_t)w * 65536 + (size_t)l * 16;
    LD4A(0);  LD4A(1);  LD4A(2);  LD4A(3);
    LD4A(4);  LD4A(5);  LD4A(6);  LD4A(7);
    LD4A(8);  LD4A(9);  LD4A(10); LD4A(11);
    LD4A(12); LD4A(13); LD4A(14); LD4A(15);
    asm volatile("s_waitcnt vmcnt(0)" ::: "memory");
  }
  // ---- weights jidx 2 -> arch VGPRs (32 frags) ---------------------------
  short8 wv[32];
#pragma unroll
  for (int q = 0; q < 32; ++q)
    wv[q] = *(const short8*)(wf + (size_t)(256 + w * 32 + q) * 512 + (size_t)l * 8);
  // ---- weights jidx 3 -> LDS, lane-linear --------------------------------
#pragma unroll
  for (int s = 0; s < 32; ++s)
    *(short8*)(ldsW + (size_t)((w * 32 + s) << 10) + l * 16) =
        *(const short8*)(wf + (size_t)(384 + w * 32 + s) * 512 + (size_t)l * 8);

  // ---- h / c init ---------------------------------------------------------
  float carr[4];
  if (first) {
    for (int i = threadIdx.x; i < (2 * HB_SZ) / 4; i += 256)
      ((unsigned int*)hb0)[i] = 0u;
#pragma unroll
    for (int j = 0; j < 4; ++j) carr[j] = 0.0f;
  } else {
#pragma unroll
    for (int jidx = 0; jidx < 4; ++jidx) {
      const int jt = jts[jidx];
      const size_t idx = (size_t)(bg * 4 + bloc) * 256 + jt * 16 + col;
      carr[jidx] = cstate[idx];
      const float hv = hstate[idx];
      *(unsigned short*)(hb0 + bloc * HB_ROW + (jt * 16 + col) * 2) =
          (unsigned short)cvt_pk_bf16(hv, hv);
    }
  }

  // ---- prefetch gx(t=0) ----------------------------------------------------
  unsigned int gxA[8], gxB[8];
  {
    const unsigned int* g0 = gx + (size_t)bg * 2048 + l;
#pragma unroll
    for (int g = 0; g < 4; ++g) {
      gxA[g] = g0[(w + 8 * g) * 64];        // jt pair {2w,2w+1}, gate g
      gxA[4 + g] = g0[(w + 4 + 8 * g) * 64];// jt pair {2w+8,2w+9}, gate g
    }
  }
  __syncthreads();

  float* outp = out + (size_t)(bg * 4 + bloc) * 256 + col;
  const int aoff = ((l & 15) >> 2) * HB_ROW + (l >> 4) * 16;  // A-frag read
  const int hwoff = bloc * HB_ROW;

  auto STEP = [&](int t, char* hbR, char* hbW, unsigned int(&gxC)[8],
                  unsigned int(&gxN)[8]) {
    // issue next-step gx prefetch (stays in flight across the raw barrier)
    const int tn = (t + 1 < 512) ? (t + 1) : 511;
    const unsigned int* gn = gx + (size_t)tn * 32768 + (size_t)bg * 2048 + l;
#pragma unroll
    for (int g = 0; g < 4; ++g) {
      gxN[g] = gn[(w + 8 * g) * 64];
      gxN[4 + g] = gn[(w + 4 + 8 * g) * 64];
    }

    // load the step's A-frags ONCE, reuse across all 4 coltiles
    const char* hrd = hbR + aoff;
    short8 af[8];
#pragma unroll
    for (int kt = 0; kt < 8; ++kt)
      af[kt] = *(const short8*)(hrd + kt * 64);

    // shared epilogue: gates -> c,h update -> global out + LDS h write
    auto EPI = [&](int jidx, float s0, float s1, float s2, float s3) {
      const int jt = jts[jidx];
      const int base = (jidx >> 1) * 4;
      const bool hi = (jidx & 1) != 0;  // odd jt -> hi half of packed dword
      const float g0f = hi ? __uint_as_float(gxC[base + 0] & 0xffff0000u)
                           : __uint_as_float(gxC[base + 0] << 16);
      const float g1f = hi ? __uint_as_float(gxC[base + 1] & 0xffff0000u)
                           : __uint_as_float(gxC[base + 1] << 16);
      const float g2f = hi ? __uint_as_float(gxC[base + 2] & 0xffff0000u)
                           : __uint_as_float(gxC[base + 2] << 16);
      const float g3f = hi ? __uint_as_float(gxC[base + 3] & 0xffff0000u)
                           : __uint_as_float(gxC[base + 3] << 16);
      const float gi = sigmoid_scaled(s0 + g0f);
      const float go = sigmoid_scaled(s1 + g1f);
      const float gz = sigmoid_scaled(s2 + g2f);
      const float gf = sigmoid_scaled(s3 + g3f);
      carr[jidx] = gf * carr[jidx] + (gz - gi);
      const float hs = sigmoid_scaled(carr[jidx] * NEG_LOG2E);
      const float hn = hs - go;
      outp[(size_t)t * 16384 + jt * 16] = hn;
      *(unsigned short*)(hbW + hwoff + (jt * 16 + col) * 2) =
          (unsigned short)cvt_pk_bf16(hn, hn);
    };

    // ---- asm region FIRST: groups jidx 0,1 (weights in AGPR) ----
    f32x4 q0 = {0.f, 0.f, 0.f, 0.f}, q1 = q0, q2 = q0, q3 = q0;
    f32x4 q4 = q0, q5 = q0, q6 = q0, q7 = q0;
    mfma4_first(af[0], wa[0], wa[8], wa[16], wa[24], q0, q1, q2, q3);
#pragma unroll
    for (int kt = 1; kt < 7; ++kt) {
      q0 = mfma_ab(af[kt], wa[kt],      q0);
      q1 = mfma_ab(af[kt], wa[8 + kt],  q1);
      q2 = mfma_ab(af[kt], wa[16 + kt], q2);
      q3 = mfma_ab(af[kt], wa[24 + kt], q3);
    }
    mfma4_last(af[7], wa[7], wa[15], wa[23], wa[31], q0, q1, q2, q3);
    mfma4_first(af[0], wa[32], wa[40], wa[48], wa[56], q4, q5, q6, q7);
#pragma unroll
    for (int kt = 1; kt < 7; ++kt) {
      q4 = mfma_ab(af[kt], wa[32 + kt], q4);
      q5 = mfma_ab(af[kt], wa[40 + kt], q5);
      q6 = mfma_ab(af[kt], wa[48 + kt], q6);
      q7 = mfma_ab(af[kt], wa[56 + kt], q7);
    }
    mfma4_last(af[7], wa[39], wa[47], wa[55], wa[63], q4, q5, q6, q7);

    // ---- weave region: intrinsic MFMAs (groups 2,3) + EPI(0..2) ----
    // All intrinsic/VALU -> the MI scheduler interleaves EPI VALU into the
    // MFMA latency shadows.  EPI(0)/EPI(1) inputs (q*) became ready at the
    // end of the asm region (nop tails inside mfma4_last cover the hazard).
    {
      f32x4 a0 = {0.f, 0.f, 0.f, 0.f}, a1 = a0, a2 = a0, a3 = a0;
#pragma unroll
      for (int kt = 0; kt < 8; ++kt) {
        a0 = MFMA_BF16(af[kt], wv[kt], a0, 0, 0, 0);
        a1 = MFMA_BF16(af[kt], wv[8 + kt], a1, 0, 0, 0);
        a2 = MFMA_BF16(af[kt], wv[16 + kt], a2, 0, 0, 0);
        a3 = MFMA_BF16(af[kt], wv[24 + kt], a3, 0, 0, 0);
      }
      EPI(0, q0[0], q1[0], q2[0], q3[0]);
      EPI(1, q4[0], q5[0], q6[0], q7[0]);

      f32x4 b0 = {0.f, 0.f, 0.f, 0.f}, b1 = b0, b2 = b0, b3 = b0;
#pragma unroll
      for (int kt = 0; kt < 8; ++kt) {
        const char* wb = ldsW + (size_t)((w * 32 + kt) << 10) + l * 16;
        b0 = MFMA_BF16(af[kt], *(const short8*)(wb), b0, 0, 0, 0);
        b1 = MFMA_BF16(af[kt], *(const short8*)(wb + (8 << 10)), b1, 0, 0, 0);
        b2 = MFMA_BF16(af[kt], *(const short8*)(wb + (16 << 10)), b2, 0, 0, 0);
        b3 = MFMA_BF16(af[kt], *(const short8*)(wb + (24 << 10)), b3, 0, 0, 0);
      }
      EPI(2, a0[0], a1[0], a2[0], a3[0]);
      EPI(3, b0[0], b1[0], b2[0], b3[0]);
    }

    // raw barrier: LDS-only drain (NO "memory" clobber -> no vmcnt(0));
    // gx prefetch loads and out stores stay in flight across the barrier.
    // sched_barrier pins the h ds_writes above the lgkmcnt+barrier.
    __builtin_amdgcn_sched_barrier(0);
    asm volatile("s_waitcnt lgkmcnt(0)");
    __builtin_amdgcn_s_barrier();
    __builtin_amdgcn_sched_barrier(0);
  };

  for (int tt = 0; tt < 256; ++tt) {
    STEP(2 * tt, hb0, hb1, gxA, gxB);
    STEP(2 * tt + 1, hb1, hb0, gxB, gxA);
  }

  // ---- save state for next chunk (h handoff via bf16 == in-chunk path) ----
#pragma unroll
  for (int jidx = 0; jidx < 4; ++jidx) {
    const int jt = jts[jidx];
    const size_t idx = (size_t)(bg * 4 + bloc) * 256 + jt * 16 + col;
    const unsigned short hb =
        *(const unsigned short*)(hb0 + hwoff + (jt * 16 + col) * 2);
    hstate[idx] = __uint_as_float((unsigned int)hb << 16);
    cstate[idx] = carr[jidx];
  }
}

// ===========================================================================
// Host launcher.  ws layout:
//   [0,512K)        wfrag bf16 (A region 0-255, V region 256-383, L 384-511)
//   [512K,576K)     hstate fp32 [64][256]
//   [576K,640K)     cstate fp32 [64][256]
//   [1M, 1M+64M)    gx chunk (512 steps, bf16-packed dwords)
// 4 chunks of 512 steps: gemm then scan, state carried in ws.
// ===========================================================================
extern "C" void kernel_launch(void* const* d_in, const int* in_sizes, int n_in,
                              void* d_out, int out_size, void* d_ws,
                              size_t ws_size, hipStream_t stream) {
  const float* x = (const float*)d_in[0];     // [2048][64][256]
  const float* w_in = (const float*)d_in[1];  // [1024][256]
  const float* bias = (const float*)d_in[2];  // [1024]
  const float* wrec = (const float*)d_in[3];  // [1024][256]
  float* out = (float*)d_out;                 // [2048][64][256]
  char* ws = (char*)d_ws;

  unsigned short* wf = (unsigned short*)ws;
  float* hstate = (float*)(ws + (512 << 10));
  float* cstate = (float*)(ws + (576 << 10));
  unsigned int* gxb = (unsigned int*)(ws + (1 << 20));

  (void)in_sizes; (void)n_in; (void)out_size; (void)ws_size;

  hipFuncSetAttribute((const void*)rnn_scan,
                      hipFuncAttributeMaxDynamicSharedMemorySize, LDS_TOTAL);

  wfrag_setup<<<dim3(512), dim3(64), 0, stream>>>(wrec, wf);

  for (int c = 0; c < 4; ++c) {
    const size_t xoff = (size_t)c * 512 * 64 * 256;
    gemm_gx<<<dim3(256, 8), dim3(256), 0, stream>>>(x + xoff, w_in, bias, gxb);
    rnn_scan<<<dim3(16), dim3(256), LDS_TOTAL, stream>>>(
        wf, gxb, out + xoff, hstate, cstate, (c == 0) ? 1 : 0);
  }
}

// Round 12
// 2618.498 us; speedup vs baseline: 2.4115x; 2.4115x over previous
//
#include <hip/hip_runtime.h>
#include <cstdint>
#include <cstddef>

typedef __attribute__((ext_vector_type(8))) short short8;
typedef __attribute__((ext_vector_type(4))) float f32x4;
typedef __attribute__((ext_vector_type(4))) unsigned int u32x4;
typedef __attribute__((ext_vector_type(4))) int i32x4;

#define NEG_LOG2E -1.44269504088896340736f
#define MFMA_BF16 __builtin_amdgcn_mfma_f32_16x16x32_bf16

// ---- helpers -------------------------------------------------------------
static __device__ __forceinline__ unsigned int cvt_pk_bf16(float lo, float hi) {
  unsigned int r;
  asm("v_cvt_pk_bf16_f32 %0, %1, %2" : "=v"(r) : "v"(lo), "v"(hi));
  return r;
}
// xs is pre-scaled by -log2(e): returns sigmoid(x_true)
static __device__ __forceinline__ float sigmoid_scaled(float xs) {
  return __builtin_amdgcn_rcpf(1.0f + __builtin_amdgcn_exp2f(xs));
}

// ---- i8 MFMA blobs (8 chains each; 2 blobs cover all 16 chains per kt) ----
// D/C in VGPR, A (h) in VGPR, B (weights) AGPR-resident.  Early-clobber
// outputs (r6 lesson).  kt=0 uses the zero-C form (D = A*B + z, z written
// once at prologue -> no per-step VALU->SrcC hazard).  The kt=3 blob of the
// second half carries the 20-cyc s_nop tail (MFMA D -> VALU read); a pinned
// external fence before the EPIs backs it up (r5-proven discipline).
static __device__ __forceinline__ void mfi8_zero(
    u32x4 af, i32x4 z, u32x4 w0, u32x4 w1, u32x4 w2, u32x4 w3, u32x4 w4,
    u32x4 w5, u32x4 w6, u32x4 w7, i32x4& c0, i32x4& c1, i32x4& c2, i32x4& c3,
    i32x4& c4, i32x4& c5, i32x4& c6, i32x4& c7) {
  asm("v_mfma_i32_16x16x64_i8 %0, %8, %10, %9\n\t"
      "v_mfma_i32_16x16x64_i8 %1, %8, %11, %9\n\t"
      "v_mfma_i32_16x16x64_i8 %2, %8, %12, %9\n\t"
      "v_mfma_i32_16x16x64_i8 %3, %8, %13, %9\n\t"
      "v_mfma_i32_16x16x64_i8 %4, %8, %14, %9\n\t"
      "v_mfma_i32_16x16x64_i8 %5, %8, %15, %9\n\t"
      "v_mfma_i32_16x16x64_i8 %6, %8, %16, %9\n\t"
      "v_mfma_i32_16x16x64_i8 %7, %8, %17, %9"
      : "=&v"(c0), "=&v"(c1), "=&v"(c2), "=&v"(c3), "=&v"(c4), "=&v"(c5),
        "=&v"(c6), "=&v"(c7)
      : "v"(af), "v"(z), "a"(w0), "a"(w1), "a"(w2), "a"(w3), "a"(w4),
        "a"(w5), "a"(w6), "a"(w7));
}
#define MFI8_ACC_BODY                                   \
  "v_mfma_i32_16x16x64_i8 %0, %8, %9, %0\n\t"           \
  "v_mfma_i32_16x16x64_i8 %1, %8, %10, %1\n\t"          \
  "v_mfma_i32_16x16x64_i8 %2, %8, %11, %2\n\t"          \
  "v_mfma_i32_16x16x64_i8 %3, %8, %12, %3\n\t"          \
  "v_mfma_i32_16x16x64_i8 %4, %8, %13, %4\n\t"          \
  "v_mfma_i32_16x16x64_i8 %5, %8, %14, %5\n\t"          \
  "v_mfma_i32_16x16x64_i8 %6, %8, %15, %6\n\t"          \
  "v_mfma_i32_16x16x64_i8 %7, %8, %16, %7"
#define MFI8_OUTS                                                         \
  "+&v"(c0), "+&v"(c1), "+&v"(c2), "+&v"(c3), "+&v"(c4), "+&v"(c5),       \
  "+&v"(c6), "+&v"(c7)
#define MFI8_INS                                                          \
  "v"(af), "a"(w0), "a"(w1), "a"(w2), "a"(w3), "a"(w4), "a"(w5), "a"(w6), \
  "a"(w7)
static __device__ __forceinline__ void mfi8_acc(
    u32x4 af, u32x4 w0, u32x4 w1, u32x4 w2, u32x4 w3, u32x4 w4, u32x4 w5,
    u32x4 w6, u32x4 w7, i32x4& c0, i32x4& c1, i32x4& c2, i32x4& c3,
    i32x4& c4, i32x4& c5, i32x4& c6, i32x4& c7) {
  asm(MFI8_ACC_BODY : MFI8_OUTS : MFI8_INS);
}
static __device__ __forceinline__ void mfi8_last(
    u32x4 af, u32x4 w0, u32x4 w1, u32x4 w2, u32x4 w3, u32x4 w4, u32x4 w5,
    u32x4 w6, u32x4 w7, i32x4& c0, i32x4& c1, i32x4& c2, i32x4& c3,
    i32x4& c4, i32x4& c5, i32x4& c6, i32x4& c7) {
  asm(MFI8_ACC_BODY "\n\ts_nop 7\n\ts_nop 7\n\ts_nop 3" : MFI8_OUTS : MFI8_INS);
}

// ===========================================================================
// Kernel 0: per-output-column scales.  Column j (0..1023) of w' = w*NEG_LOG2E:
// s_j = max_k |w'[j,k]|.  scbuf[j] = s_j/(127*127) (EPI dequant multiplier,
// folds h's 1/127), w127[j] = 127/s_j (quantizer multiplier).
// ===========================================================================
__global__ void wscale_setup(const float* __restrict__ w_rec,
                             float* __restrict__ scbuf,
                             float* __restrict__ w127) {
  const int j = blockIdx.x * 64 + threadIdx.x;  // 0..1023
  const float* row = w_rec + (size_t)j * 256;
  float m = 0.f;
  for (int k = 0; k < 256; ++k) m = fmaxf(m, fabsf(row[k]));
  float s = fmaxf(m * 1.44269504088896f, 1e-30f);
  scbuf[j] = s / 16129.0f;
  w127[j] = 127.0f / s;
}

// ===========================================================================
// Kernel 1: quantize w_rec -> i8 fragment buffer for mfma_i32_16x16x64_i8.
// 256 slots of 1 KB; slot f = w*64 + q, q = chain*4 + kt (chain = jidx*4+g,
// kt = K-tile of 64).  jts(w) = {2w, 2w+1, 2w+8, 2w+9}; ct = jt + 16g.
// Lane l, dwords d0..3, bytes e: q_w[col = ct*16 + (l&15)]
//                                   [k = kt*64 + (l>>4)*16 + 4d + e]
// (natural extension of the verified bf16 16x16x32 B layout: col=l&15,
//  k-group = l>>4, contiguous k per lane.)
// ===========================================================================
__global__ void wfrag_setup_i8(const float* __restrict__ w_rec,
                               const float* __restrict__ w127,
                               unsigned int* __restrict__ wfq) {
  const int f = blockIdx.x;   // 0..255
  const int l = threadIdx.x;  // 0..63
  const int w = f >> 6, q = f & 63;
  const int chain = q >> 2, kt = q & 3;
  const int jidx = chain >> 2, g = chain & 3;
  const int jt = (jidx < 2) ? (2 * w + jidx) : (2 * w + 8 + (jidx - 2));
  const int ct = jt + 16 * g;
  const int j = ct * 16 + (l & 15);
  const float r = w127[j];
  const float* src = w_rec + (size_t)j * 256 + kt * 64 + (l >> 4) * 16;
  u32x4 ov;
#pragma unroll
  for (int d = 0; d < 4; ++d) {
    unsigned int word = 0;
#pragma unroll
    for (int e = 0; e < 4; ++e) {
      int qi = (int)rintf(src[4 * d + e] * NEG_LOG2E * r);
      qi = qi > 127 ? 127 : (qi < -127 ? -127 : qi);
      word |= ((unsigned int)(qi & 255)) << (8 * e);
    }
    ov[d] = word;
  }
  *(u32x4*)(wfq + (size_t)f * 256 + (size_t)l * 4) = ov;
}

// ===========================================================================
// Kernel 2: gx = (x @ w_in^T + b) * -log2(e), bf16-packed in the layout the
// RNN consumes (r1-verified, unchanged).
// ===========================================================================
static __device__ __forceinline__ short8 ldcvt8(const float* p) {
  f32x4 v0 = *(const f32x4*)p;
  f32x4 v1 = *(const f32x4*)(p + 4);
  u32x4 u;
  u[0] = cvt_pk_bf16(v0[0], v0[1]);
  u[1] = cvt_pk_bf16(v0[2], v0[3]);
  u[2] = cvt_pk_bf16(v1[0], v1[1]);
  u[3] = cvt_pk_bf16(v1[2], v1[3]);
  return __builtin_bit_cast(short8, u);
}

__global__ __launch_bounds__(256) void gemm_gx(const float* __restrict__ x,
                                               const float* __restrict__ w_in,
                                               const float* __restrict__ bias,
                                               unsigned int* __restrict__ gx) {
  const int l = threadIdx.x & 63, wid = threadIdx.x >> 6;
  const int mq = wid >> 1, nq = wid & 1;
  const int mbase = blockIdx.x * 128 + mq * 64;
  const int nbase = blockIdx.y * 128 + nq * 64;
  const int lr = l & 15;
  const int lk = (l >> 4) * 8;

  f32x4 acc[4][4] = {};
#pragma unroll
  for (int kt = 0; kt < 8; ++kt) {
    const int k0 = kt * 32 + lk;
    short8 af[4], bf[4];
#pragma unroll
    for (int mt = 0; mt < 4; ++mt)
      af[mt] = ldcvt8(x + (size_t)(mbase + mt * 16 + lr) * 256 + k0);
#pragma unroll
    for (int nt = 0; nt < 4; ++nt)
      bf[nt] = ldcvt8(w_in + (size_t)(nbase + nt * 16 + lr) * 256 + k0);
#pragma unroll
    for (int mt = 0; mt < 4; ++mt)
#pragma unroll
      for (int nt = 0; nt < 4; ++nt)
        acc[mt][nt] = MFMA_BF16(af[mt], bf[nt], acc[mt][nt], 0, 0, 0);
  }

  float bv[4];
#pragma unroll
  for (int nt = 0; nt < 4; ++nt) bv[nt] = bias[nbase + nt * 16 + lr];

#pragma unroll
  for (int mt = 0; mt < 4; ++mt) {
    const int m0 = mbase + mt * 16;
    const int tt = m0 >> 6;
    const int bg = ((m0 & 63) >> 2) + (l >> 4);
#pragma unroll
    for (int ntp = 0; ntp < 2; ++ntp) {
      const int p = (nbase >> 5) + ntp;
#pragma unroll
      for (int r = 0; r < 4; ++r) {
        float e0 = (acc[mt][ntp * 2 + 0][r] + bv[ntp * 2 + 0]) * NEG_LOG2E;
        float e1 = (acc[mt][ntp * 2 + 1][r] + bv[ntp * 2 + 1]) * NEG_LOG2E;
        gx[(((size_t)tt * 16 + bg) * 32 + p) * 64 + (r * 16 + lr)] =
            cvt_pk_bf16(e0, e1);
      }
    }
  }
}

// ===========================================================================
// Kernel 3: scan, r5 geometry (16 blocks x 4 waves) but i8 recurrence:
//   ALL 64 weight frags/wave live in AGPRs (exactly 256) -- no LDS weights,
//   no perm weight VGPRs -> arch VGPR pressure ~150 (ends the r9-r11 NaNs).
//   64 MFMAs/step (K=64) instead of 128; LDS ops/step drop from 44 to 8.
//   h stored as i8 in a tiny 2x1088B ping-pong; per-column dequant scales
//   applied in the EPI (scv[16] per thread).
// ===========================================================================
#define HB8_ROW 272                      // 256B h-row + 16B pad
#define HB8_SZ (4 * HB8_ROW)             // 1088
#define LDS_TOTAL (2 * HB8_SZ)           // 2176

#define LD4A(i)                                                         \
  asm volatile("global_load_dwordx4 %0, %4, off\n\t"                    \
               "global_load_dwordx4 %1, %4, off offset:1024\n\t"        \
               "global_load_dwordx4 %2, %4, off offset:2048\n\t"        \
               "global_load_dwordx4 %3, %4, off offset:3072"            \
               : "=&a"(wa[4 * (i)]), "=&a"(wa[4 * (i) + 1]),            \
                 "=&a"(wa[4 * (i) + 2]), "=&a"(wa[4 * (i) + 3])         \
               : "v"(pA + 4096 * (i)))

__global__ __launch_bounds__(256, 1) void rnn_scan(
    const unsigned int* __restrict__ wfq, const float* __restrict__ scbuf,
    const unsigned int* __restrict__ gx, float* __restrict__ out,
    float* __restrict__ hstate, float* __restrict__ cstate, int first) {
  extern __shared__ char lds[];
  char* hb0 = lds;
  char* hb1 = lds + HB8_SZ;

  const int l = threadIdx.x & 63;
  const int w = threadIdx.x >> 6;
  const int bg = blockIdx.x;      // 0..15 -> batches 4bg..4bg+3
  const int bloc = l >> 4;        // local batch 0..3
  const int col = l & 15;
  const int jts[4] = {2 * w, 2 * w + 1, 2 * w + 8, 2 * w + 9};

  // ---- all 64 weight frags -> AGPR (256 regs exactly) --------------------
  u32x4 wa[64];
  {
    const char* pA = (const char*)wfq + (size_t)w * 65536 + (size_t)l * 16;
    LD4A(0);  LD4A(1);  LD4A(2);  LD4A(3);
    LD4A(4);  LD4A(5);  LD4A(6);  LD4A(7);
    LD4A(8);  LD4A(9);  LD4A(10); LD4A(11);
    LD4A(12); LD4A(13); LD4A(14); LD4A(15);
    asm volatile("s_waitcnt vmcnt(0)" ::: "memory");
  }
  // ---- per-column dequant scales (16 per thread) -------------------------
  float scv[16];
#pragma unroll
  for (int jidx = 0; jidx < 4; ++jidx)
#pragma unroll
    for (int g = 0; g < 4; ++g)
      scv[jidx * 4 + g] = scbuf[(jts[jidx] + 16 * g) * 16 + col];

  // ---- h / c init ---------------------------------------------------------
  float carr[4];
  if (first) {
    for (int i = threadIdx.x; i < (2 * HB8_SZ) / 4; i += 256)
      ((unsigned int*)hb0)[i] = 0u;
#pragma unroll
    for (int j = 0; j < 4; ++j) carr[j] = 0.0f;
  } else {
#pragma unroll
    for (int jidx = 0; jidx < 4; ++jidx) {
      const int jt = jts[jidx];
      const size_t idx = (size_t)(bg * 4 + bloc) * 256 + jt * 16 + col;
      carr[jidx] = cstate[idx];
      const int qi = (int)rintf(hstate[idx] * 127.f);
      *(char*)(hb0 + bloc * HB8_ROW + jt * 16 + col) = (char)qi;
    }
  }

  i32x4 z4 = {0, 0, 0, 0};  // shared zero-C operand, written once

  // ---- prefetch gx(t=0) ----------------------------------------------------
  unsigned int gxA[8], gxB[8];
  {
    const unsigned int* g0 = gx + (size_t)bg * 2048 + l;
#pragma unroll
    for (int g = 0; g < 4; ++g) {
      gxA[g] = g0[(w + 8 * g) * 64];         // jt pair {2w,2w+1}, gate g
      gxA[4 + g] = g0[(w + 4 + 8 * g) * 64]; // jt pair {2w+8,2w+9}, gate g
    }
  }
  __syncthreads();

  float* outp = out + (size_t)(bg * 4 + bloc) * 256 + col;
  const int aoff = ((l & 15) >> 2) * HB8_ROW + (l >> 4) * 16;  // A-frag read
  const int hwoff = bloc * HB8_ROW;

  auto STEP = [&](int t, char* hbR, char* hbW, unsigned int(&gxC)[8],
                  unsigned int(&gxN)[8]) {
    // next-step gx prefetch (stays in flight across the raw barrier)
    const int tn = (t + 1 < 512) ? (t + 1) : 511;
    const unsigned int* gn = gx + (size_t)tn * 32768 + (size_t)bg * 2048 + l;
#pragma unroll
    for (int g = 0; g < 4; ++g) {
      gxN[g] = gn[(w + 8 * g) * 64];
      gxN[4 + g] = gn[(w + 4 + 8 * g) * 64];
    }

    // A-frags (i8 h): 4 x ds_read_b128 covers K=256
    const char* hrd = hbR + aoff;
    const u32x4 af0 = *(const u32x4*)(hrd);
    const u32x4 af1 = *(const u32x4*)(hrd + 64);
    const u32x4 af2 = *(const u32x4*)(hrd + 128);
    const u32x4 af3 = *(const u32x4*)(hrd + 192);

    // ---- 16 chains x 4 kt, all-asm, weights AGPR-resident ----
    i32x4 c0, c1, c2, c3, c4, c5, c6, c7, c8, c9, c10, c11, c12, c13, c14, c15;
    mfi8_zero(af0, z4, wa[0], wa[4], wa[8], wa[12], wa[16], wa[20], wa[24],
              wa[28], c0, c1, c2, c3, c4, c5, c6, c7);
    mfi8_zero(af0, z4, wa[32], wa[36], wa[40], wa[44], wa[48], wa[52], wa[56],
              wa[60], c8, c9, c10, c11, c12, c13, c14, c15);
    mfi8_acc(af1, wa[1], wa[5], wa[9], wa[13], wa[17], wa[21], wa[25], wa[29],
             c0, c1, c2, c3, c4, c5, c6, c7);
    mfi8_acc(af1, wa[33], wa[37], wa[41], wa[45], wa[49], wa[53], wa[57],
             wa[61], c8, c9, c10, c11, c12, c13, c14, c15);
    mfi8_acc(af2, wa[2], wa[6], wa[10], wa[14], wa[18], wa[22], wa[26], wa[30],
             c0, c1, c2, c3, c4, c5, c6, c7);
    mfi8_acc(af2, wa[34], wa[38], wa[42], wa[46], wa[50], wa[54], wa[58],
             wa[62], c8, c9, c10, c11, c12, c13, c14, c15);
    mfi8_acc(af3, wa[3], wa[7], wa[11], wa[15], wa[19], wa[23], wa[27], wa[31],
             c0, c1, c2, c3, c4, c5, c6, c7);
    mfi8_last(af3, wa[35], wa[39], wa[43], wa[47], wa[51], wa[55], wa[59],
              wa[63], c8, c9, c10, c11, c12, c13, c14, c15);

    // pinned fence: asm-MFMA D write -> EPI VALU read
    __builtin_amdgcn_sched_barrier(0);
    asm volatile("s_nop 7\n\ts_nop 7\n\ts_nop 3" :::);
    __builtin_amdgcn_sched_barrier(0);

    // epilogue: dequant -> gates -> c,h update -> global out + LDS i8 h
    auto EPI = [&](int jidx, i32x4 s0, i32x4 s1, i32x4 s2, i32x4 s3) {
      const int jt = jts[jidx];
      const int base = (jidx >> 1) * 4;
      const bool hi = (jidx & 1) != 0;
      const float g0f = hi ? __uint_as_float(gxC[base + 0] & 0xffff0000u)
                           : __uint_as_float(gxC[base + 0] << 16);
      const float g1f = hi ? __uint_as_float(gxC[base + 1] & 0xffff0000u)
                           : __uint_as_float(gxC[base + 1] << 16);
      const float g2f = hi ? __uint_as_float(gxC[base + 2] & 0xffff0000u)
                           : __uint_as_float(gxC[base + 2] << 16);
      const float g3f = hi ? __uint_as_float(gxC[base + 3] & 0xffff0000u)
                           : __uint_as_float(gxC[base + 3] << 16);
      const float gi = sigmoid_scaled(fmaf((float)s0[0], scv[jidx * 4 + 0], g0f));
      const float go = sigmoid_scaled(fmaf((float)s1[0], scv[jidx * 4 + 1], g1f));
      const float gz = sigmoid_scaled(fmaf((float)s2[0], scv[jidx * 4 + 2], g2f));
      const float gf = sigmoid_scaled(fmaf((float)s3[0], scv[jidx * 4 + 3], g3f));
      carr[jidx] = gf * carr[jidx] + (gz - gi);
      const float hs = sigmoid_scaled(carr[jidx] * NEG_LOG2E);
      const float hn = hs - go;
      outp[(size_t)t * 16384 + jt * 16] = hn;
      const int qh = (int)rintf(hn * 127.f);
      *(char*)(hbW + hwoff + jt * 16 + col) = (char)qh;
    };
    EPI(0, c0, c1, c2, c3);
    EPI(1, c4, c5, c6, c7);
    EPI(2, c8, c9, c10, c11);
    EPI(3, c12, c13, c14, c15);

    // raw barrier: LDS-only drain (no "memory" clobber -> no vmcnt(0));
    // gx prefetch loads and out stores stay in flight across the barrier.
    __builtin_amdgcn_sched_barrier(0);
    asm volatile("s_waitcnt lgkmcnt(0)");
    __builtin_amdgcn_s_barrier();
    __builtin_amdgcn_sched_barrier(0);
  };

  for (int tt = 0; tt < 256; ++tt) {
    STEP(2 * tt, hb0, hb1, gxA, gxB);
    STEP(2 * tt + 1, hb1, hb0, gxB, gxA);
  }

  // ---- save state (h via i8 roundtrip == in-chunk path) -------------------
#pragma unroll
  for (int jidx = 0; jidx < 4; ++jidx) {
    const int jt = jts[jidx];
    const size_t idx = (size_t)(bg * 4 + bloc) * 256 + jt * 16 + col;
    const signed char qv =
        *(const signed char*)(hb0 + hwoff + jt * 16 + col);
    hstate[idx] = (float)qv / 127.f;
    cstate[idx] = carr[jidx];
  }
}

// ===========================================================================
// Host launcher.  ws layout:
//   [0,256K)        wfq i8 frags
//   [256K,260K)     scbuf (1024 f32)
//   [260K,264K)     w127 (1024 f32)
//   [512K,576K)     hstate fp32 [64][256]
//   [576K,640K)     cstate fp32 [64][256]
//   [1M, 1M+64M)    gx chunk (512 steps, bf16-packed dwords)
// ===========================================================================
extern "C" void kernel_launch(void* const* d_in, const int* in_sizes, int n_in,
                              void* d_out, int out_size, void* d_ws,
                              size_t ws_size, hipStream_t stream) {
  const float* x = (const float*)d_in[0];     // [2048][64][256]
  const float* w_in = (const float*)d_in[1];  // [1024][256]
  const float* bias = (const float*)d_in[2];  // [1024]
  const float* wrec = (const float*)d_in[3];  // [1024][256]
  float* out = (float*)d_out;                 // [2048][64][256]
  char* ws = (char*)d_ws;

  unsigned int* wfq = (unsigned int*)ws;
  float* scbuf = (float*)(ws + (256 << 10));
  float* w127 = (float*)(ws + (260 << 10));
  float* hstate = (float*)(ws + (512 << 10));
  float* cstate = (float*)(ws + (576 << 10));
  unsigned int* gxb = (unsigned int*)(ws + (1 << 20));

  (void)in_sizes; (void)n_in; (void)out_size; (void)ws_size;

  wscale_setup<<<dim3(16), dim3(64), 0, stream>>>(wrec, scbuf, w127);
  wfrag_setup_i8<<<dim3(256), dim3(64), 0, stream>>>(wrec, w127, wfq);

  for (int c = 0; c < 4; ++c) {
    const size_t xoff = (size_t)c * 512 * 64 * 256;
    gemm_gx<<<dim3(256, 8), dim3(256), 0, stream>>>(x + xoff, w_in, bias, gxb);
    rnn_scan<<<dim3(16), dim3(256), LDS_TOTAL, stream>>>(
        wfq, scbuf, gxb, out + xoff, hstate, cstate, (c == 0) ? 1 : 0);
  }
}

// Round 13
// 2539.796 us; speedup vs baseline: 2.4863x; 1.0310x over previous
//
#include <hip/hip_runtime.h>
#include <cstdint>
#include <cstddef>

typedef __attribute__((ext_vector_type(8))) short short8;
typedef __attribute__((ext_vector_type(4))) float f32x4;
typedef __attribute__((ext_vector_type(4))) unsigned int u32x4;
typedef __attribute__((ext_vector_type(4))) int i32x4;

#define NEG_LOG2E -1.44269504088896340736f
#define MFMA_BF16 __builtin_amdgcn_mfma_f32_16x16x32_bf16
#define MFMA_I8 __builtin_amdgcn_mfma_i32_16x16x64_i8

// ---- helpers -------------------------------------------------------------
static __device__ __forceinline__ unsigned int cvt_pk_bf16(float lo, float hi) {
  unsigned int r;
  asm("v_cvt_pk_bf16_f32 %0, %1, %2" : "=v"(r) : "v"(lo), "v"(hi));
  return r;
}
// xs is pre-scaled by -log2(e): returns sigmoid(x_true)
static __device__ __forceinline__ float sigmoid_scaled(float xs) {
  return __builtin_amdgcn_rcpf(1.0f + __builtin_amdgcn_exp2f(xs));
}

// ===========================================================================
// Kernel 0: per-output-column scales.  Column j (0..1023) of w' = w*NEG_LOG2E:
// s_j = max_k |w'[j,k]|.  scbuf[j] = s_j/(127*127) (EPI dequant multiplier,
// folds h's 1/127), w127[j] = 127/s_j (quantizer multiplier).
// ===========================================================================
__global__ void wscale_setup(const float* __restrict__ w_rec,
                             float* __restrict__ scbuf,
                             float* __restrict__ w127) {
  const int j = blockIdx.x * 64 + threadIdx.x;  // 0..1023
  const float* row = w_rec + (size_t)j * 256;
  float m = 0.f;
  for (int k = 0; k < 256; ++k) m = fmaxf(m, fabsf(row[k]));
  float s = fmaxf(m * 1.44269504088896f, 1e-30f);
  scbuf[j] = s / 16129.0f;
  w127[j] = 127.0f / s;
}

// ===========================================================================
// Kernel 1: quantize w_rec -> i8 fragment buffer for mfma_i32_16x16x64_i8.
// 256 slots of 1 KB; slot f = w*64 + q, q = chain*4 + kt (chain = jidx*4+g,
// kt = K-tile of 64).  jts(w) = {2w, 2w+1, 2w+8, 2w+9}; ct = jt + 16g.
// Lane l, dwords d0..3, bytes e: q_w[col = ct*16 + (l&15)]
//                                   [k = kt*64 + (l>>4)*16 + 4d + e]
// (r12-verified layout)
// ===========================================================================
__global__ void wfrag_setup_i8(const float* __restrict__ w_rec,
                               const float* __restrict__ w127,
                               unsigned int* __restrict__ wfq) {
  const int f = blockIdx.x;   // 0..255
  const int l = threadIdx.x;  // 0..63
  const int w = f >> 6, q = f & 63;
  const int chain = q >> 2, kt = q & 3;
  const int jidx = chain >> 2, g = chain & 3;
  const int jt = (jidx < 2) ? (2 * w + jidx) : (2 * w + 8 + (jidx - 2));
  const int ct = jt + 16 * g;
  const int j = ct * 16 + (l & 15);
  const float r = w127[j];
  const float* src = w_rec + (size_t)j * 256 + kt * 64 + (l >> 4) * 16;
  u32x4 ov;
#pragma unroll
  for (int d = 0; d < 4; ++d) {
    unsigned int word = 0;
#pragma unroll
    for (int e = 0; e < 4; ++e) {
      int qi = (int)rintf(src[4 * d + e] * NEG_LOG2E * r);
      qi = qi > 127 ? 127 : (qi < -127 ? -127 : qi);
      word |= ((unsigned int)(qi & 255)) << (8 * e);
    }
    ov[d] = word;
  }
  *(u32x4*)(wfq + (size_t)f * 256 + (size_t)l * 4) = ov;
}

// ===========================================================================
// Kernel 2: gx = (x @ w_in^T + b) * -log2(e), bf16-packed in the layout the
// RNN consumes (r1-verified, unchanged).
// ===========================================================================
static __device__ __forceinline__ short8 ldcvt8(const float* p) {
  f32x4 v0 = *(const f32x4*)p;
  f32x4 v1 = *(const f32x4*)(p + 4);
  u32x4 u;
  u[0] = cvt_pk_bf16(v0[0], v0[1]);
  u[1] = cvt_pk_bf16(v0[2], v0[3]);
  u[2] = cvt_pk_bf16(v1[0], v1[1]);
  u[3] = cvt_pk_bf16(v1[2], v1[3]);
  return __builtin_bit_cast(short8, u);
}

__global__ __launch_bounds__(256) void gemm_gx(const float* __restrict__ x,
                                               const float* __restrict__ w_in,
                                               const float* __restrict__ bias,
                                               unsigned int* __restrict__ gx) {
  const int l = threadIdx.x & 63, wid = threadIdx.x >> 6;
  const int mq = wid >> 1, nq = wid & 1;
  const int mbase = blockIdx.x * 128 + mq * 64;
  const int nbase = blockIdx.y * 128 + nq * 64;
  const int lr = l & 15;
  const int lk = (l >> 4) * 8;

  f32x4 acc[4][4] = {};
#pragma unroll
  for (int kt = 0; kt < 8; ++kt) {
    const int k0 = kt * 32 + lk;
    short8 af[4], bf[4];
#pragma unroll
    for (int mt = 0; mt < 4; ++mt)
      af[mt] = ldcvt8(x + (size_t)(mbase + mt * 16 + lr) * 256 + k0);
#pragma unroll
    for (int nt = 0; nt < 4; ++nt)
      bf[nt] = ldcvt8(w_in + (size_t)(nbase + nt * 16 + lr) * 256 + k0);
#pragma unroll
    for (int mt = 0; mt < 4; ++mt)
#pragma unroll
      for (int nt = 0; nt < 4; ++nt)
        acc[mt][nt] = MFMA_BF16(af[mt], bf[nt], acc[mt][nt], 0, 0, 0);
  }

  float bv[4];
#pragma unroll
  for (int nt = 0; nt < 4; ++nt) bv[nt] = bias[nbase + nt * 16 + lr];

#pragma unroll
  for (int mt = 0; mt < 4; ++mt) {
    const int m0 = mbase + mt * 16;
    const int tt = m0 >> 6;
    const int bg = ((m0 & 63) >> 2) + (l >> 4);
#pragma unroll
    for (int ntp = 0; ntp < 2; ++ntp) {
      const int p = (nbase >> 5) + ntp;
#pragma unroll
      for (int r = 0; r < 4; ++r) {
        float e0 = (acc[mt][ntp * 2 + 0][r] + bv[ntp * 2 + 0]) * NEG_LOG2E;
        float e1 = (acc[mt][ntp * 2 + 1][r] + bv[ntp * 2 + 1]) * NEG_LOG2E;
        gx[(((size_t)tt * 16 + bg) * 32 + p) * 64 + (r * 16 + lr)] =
            cvt_pk_bf16(e0, e1);
      }
    }
  }
}

// ===========================================================================
// Kernel 3: scan, r12 geometry (16 blocks x 4 waves, ALL 64 weight frags in
// AGPR).  NEW vs r12: the 64 MFMAs are INTRINSICS (weights still AGPR-born
// via "=&a" loads -- gfx950 MFMA reads B from AGPR directly, so no copies).
// The compiler now owns scheduling + hazards for the whole step body and can
// weave EPI VALU into the MFMA pipe shadows (the r12 asm blobs forced
// MFMA-then-VALU serialization: ~1000 cyc pipe + ~950 cyc VALU back-to-back).
// kt=0 uses a hoisted zero-C constant (no per-step accumulator zero-init).
// One raw s_barrier/step, LDS-only drain; gx prefetch + out stores in flight.
// ===========================================================================
#define HB8_ROW 272                      // 256B h-row + 16B pad
#define HB8_SZ (4 * HB8_ROW)             // 1088
#define LDS_TOTAL (2 * HB8_SZ)           // 2176

#define LD4A(i)                                                         \
  asm volatile("global_load_dwordx4 %0, %4, off\n\t"                    \
               "global_load_dwordx4 %1, %4, off offset:1024\n\t"        \
               "global_load_dwordx4 %2, %4, off offset:2048\n\t"        \
               "global_load_dwordx4 %3, %4, off offset:3072"            \
               : "=&a"(wa[4 * (i)]), "=&a"(wa[4 * (i) + 1]),            \
                 "=&a"(wa[4 * (i) + 2]), "=&a"(wa[4 * (i) + 3])         \
               : "v"(pA + 4096 * (i)))

__global__ __launch_bounds__(256, 1) void rnn_scan(
    const unsigned int* __restrict__ wfq, const float* __restrict__ scbuf,
    const unsigned int* __restrict__ gx, float* __restrict__ out,
    float* __restrict__ hstate, float* __restrict__ cstate, int first) {
  extern __shared__ char lds[];
  char* hb0 = lds;
  char* hb1 = lds + HB8_SZ;

  const int l = threadIdx.x & 63;
  const int w = threadIdx.x >> 6;
  const int bg = blockIdx.x;      // 0..15 -> batches 4bg..4bg+3
  const int bloc = l >> 4;        // local batch 0..3
  const int col = l & 15;
  const int jts[4] = {2 * w, 2 * w + 1, 2 * w + 8, 2 * w + 9};

  // ---- all 64 weight frags -> AGPR (256 regs exactly) --------------------
  i32x4 wa[64];
  {
    const char* pA = (const char*)wfq + (size_t)w * 65536 + (size_t)l * 16;
    LD4A(0);  LD4A(1);  LD4A(2);  LD4A(3);
    LD4A(4);  LD4A(5);  LD4A(6);  LD4A(7);
    LD4A(8);  LD4A(9);  LD4A(10); LD4A(11);
    LD4A(12); LD4A(13); LD4A(14); LD4A(15);
    asm volatile("s_waitcnt vmcnt(0)" ::: "memory");
  }
  // ---- per-column dequant scales (16 per thread) -------------------------
  float scv[16];
#pragma unroll
  for (int jidx = 0; jidx < 4; ++jidx)
#pragma unroll
    for (int g = 0; g < 4; ++g)
      scv[jidx * 4 + g] = scbuf[(jts[jidx] + 16 * g) * 16 + col];

  // ---- h / c init ---------------------------------------------------------
  float carr[4];
  if (first) {
    for (int i = threadIdx.x; i < (2 * HB8_SZ) / 4; i += 256)
      ((unsigned int*)hb0)[i] = 0u;
#pragma unroll
    for (int j = 0; j < 4; ++j) carr[j] = 0.0f;
  } else {
#pragma unroll
    for (int jidx = 0; jidx < 4; ++jidx) {
      const int jt = jts[jidx];
      const size_t idx = (size_t)(bg * 4 + bloc) * 256 + jt * 16 + col;
      carr[jidx] = cstate[idx];
      const int qi = (int)rintf(hstate[idx] * 127.f);
      *(char*)(hb0 + bloc * HB8_ROW + jt * 16 + col) = (char)qi;
    }
  }

  const i32x4 kZero = {0, 0, 0, 0};  // hoisted zero-C operand

  // ---- prefetch gx(t=0) ----------------------------------------------------
  unsigned int gxA[8], gxB[8];
  {
    const unsigned int* g0 = gx + (size_t)bg * 2048 + l;
#pragma unroll
    for (int g = 0; g < 4; ++g) {
      gxA[g] = g0[(w + 8 * g) * 64];         // jt pair {2w,2w+1}, gate g
      gxA[4 + g] = g0[(w + 4 + 8 * g) * 64]; // jt pair {2w+8,2w+9}, gate g
    }
  }
  __syncthreads();

  float* outp = out + (size_t)(bg * 4 + bloc) * 256 + col;
  const int aoff = ((l & 15) >> 2) * HB8_ROW + (l >> 4) * 16;  // A-frag read
  const int hwoff = bloc * HB8_ROW;

  auto STEP = [&](int t, char* hbR, char* hbW, unsigned int(&gxC)[8],
                  unsigned int(&gxN)[8]) {
    // next-step gx prefetch (stays in flight across the raw barrier)
    const int tn = (t + 1 < 512) ? (t + 1) : 511;
    const unsigned int* gn = gx + (size_t)tn * 32768 + (size_t)bg * 2048 + l;
#pragma unroll
    for (int g = 0; g < 4; ++g) {
      gxN[g] = gn[(w + 8 * g) * 64];
      gxN[4 + g] = gn[(w + 4 + 8 * g) * 64];
    }

    // A-frags (i8 h): 4 x ds_read_b128 covers K=256
    const char* hrd = hbR + aoff;
    i32x4 afv[4];
#pragma unroll
    for (int kt = 0; kt < 4; ++kt)
      afv[kt] = *(const i32x4*)(hrd + kt * 64);

    // epilogue: dequant -> gates -> c,h update -> global out + LDS i8 h
    auto EPI = [&](int jidx, int s0, int s1, int s2, int s3) {
      const int jt = jts[jidx];
      const int base = (jidx >> 1) * 4;
      const bool hi = (jidx & 1) != 0;
      const float g0f = hi ? __uint_as_float(gxC[base + 0] & 0xffff0000u)
                           : __uint_as_float(gxC[base + 0] << 16);
      const float g1f = hi ? __uint_as_float(gxC[base + 1] & 0xffff0000u)
                           : __uint_as_float(gxC[base + 1] << 16);
      const float g2f = hi ? __uint_as_float(gxC[base + 2] & 0xffff0000u)
                           : __uint_as_float(gxC[base + 2] << 16);
      const float g3f = hi ? __uint_as_float(gxC[base + 3] & 0xffff0000u)
                           : __uint_as_float(gxC[base + 3] << 16);
      const float gi = sigmoid_scaled(fmaf((float)s0, scv[jidx * 4 + 0], g0f));
      const float go = sigmoid_scaled(fmaf((float)s1, scv[jidx * 4 + 1], g1f));
      const float gz = sigmoid_scaled(fmaf((float)s2, scv[jidx * 4 + 2], g2f));
      const float gf = sigmoid_scaled(fmaf((float)s3, scv[jidx * 4 + 3], g3f));
      carr[jidx] = gf * carr[jidx] + (gz - gi);
      const float hs = sigmoid_scaled(carr[jidx] * NEG_LOG2E);
      const float hn = hs - go;
      outp[(size_t)t * 16384 + jt * 16] = hn;
      const int qh = (int)rintf(hn * 127.f);
      *(char*)(hbW + hwoff + jt * 16 + col) = (char)qh;
    };

    // ---- 16 chains, intrinsic MFMAs (compiler-scheduled + hazard-managed).
    // Ordered jidx-group -> EPI so the scheduler can weave EPI(j) VALU into
    // the MFMA shadows of groups j+1..3 (it may hoist MFMAs past EPI VALU).
#pragma unroll
    for (int jidx = 0; jidx < 4; ++jidx) {
      const int cb = jidx * 16;  // wa base: chain = jidx*4+g, slot chain*4+kt
      i32x4 d0 = MFMA_I8(afv[0], wa[cb + 0], kZero, 0, 0, 0);
      i32x4 d1 = MFMA_I8(afv[0], wa[cb + 4], kZero, 0, 0, 0);
      i32x4 d2 = MFMA_I8(afv[0], wa[cb + 8], kZero, 0, 0, 0);
      i32x4 d3 = MFMA_I8(afv[0], wa[cb + 12], kZero, 0, 0, 0);
#pragma unroll
      for (int kt = 1; kt < 4; ++kt) {
        d0 = MFMA_I8(afv[kt], wa[cb + kt], d0, 0, 0, 0);
        d1 = MFMA_I8(afv[kt], wa[cb + 4 + kt], d1, 0, 0, 0);
        d2 = MFMA_I8(afv[kt], wa[cb + 8 + kt], d2, 0, 0, 0);
        d3 = MFMA_I8(afv[kt], wa[cb + 12 + kt], d3, 0, 0, 0);
      }
      EPI(jidx, d0[0], d1[0], d2[0], d3[0]);
    }

    // raw barrier: LDS-only drain (no "memory" clobber -> no vmcnt(0));
    // gx prefetch loads and out stores stay in flight across the barrier.
    __builtin_amdgcn_sched_barrier(0);
    asm volatile("s_waitcnt lgkmcnt(0)");
    __builtin_amdgcn_s_barrier();
    __builtin_amdgcn_sched_barrier(0);
  };

  for (int tt = 0; tt < 256; ++tt) {
    STEP(2 * tt, hb0, hb1, gxA, gxB);
    STEP(2 * tt + 1, hb1, hb0, gxB, gxA);
  }

  // ---- save state (h via i8 roundtrip == in-chunk path) -------------------
#pragma unroll
  for (int jidx = 0; jidx < 4; ++jidx) {
    const int jt = jts[jidx];
    const size_t idx = (size_t)(bg * 4 + bloc) * 256 + jt * 16 + col;
    const signed char qv =
        *(const signed char*)(hb0 + hwoff + jt * 16 + col);
    hstate[idx] = (float)qv / 127.f;
    cstate[idx] = carr[jidx];
  }
}

// ===========================================================================
// Host launcher.  ws layout:
//   [0,256K)        wfq i8 frags
//   [256K,260K)     scbuf (1024 f32)
//   [260K,264K)     w127 (1024 f32)
//   [512K,576K)     hstate fp32 [64][256]
//   [576K,640K)     cstate fp32 [64][256]
//   [1M, 1M+64M)    gx chunk (512 steps, bf16-packed dwords)
// ===========================================================================
extern "C" void kernel_launch(void* const* d_in, const int* in_sizes, int n_in,
                              void* d_out, int out_size, void* d_ws,
                              size_t ws_size, hipStream_t stream) {
  const float* x = (const float*)d_in[0];     // [2048][64][256]
  const float* w_in = (const float*)d_in[1];  // [1024][256]
  const float* bias = (const float*)d_in[2];  // [1024]
  const float* wrec = (const float*)d_in[3];  // [1024][256]
  float* out = (float*)d_out;                 // [2048][64][256]
  char* ws = (char*)d_ws;

  unsigned int* wfq = (unsigned int*)ws;
  float* scbuf = (float*)(ws + (256 << 10));
  float* w127 = (float*)(ws + (260 << 10));
  float* hstate = (float*)(ws + (512 << 10));
  float* cstate = (float*)(ws + (576 << 10));
  unsigned int* gxb = (unsigned int*)(ws + (1 << 20));

  (void)in_sizes; (void)n_in; (void)out_size; (void)ws_size;

  wscale_setup<<<dim3(16), dim3(64), 0, stream>>>(wrec, scbuf, w127);
  wfrag_setup_i8<<<dim3(256), dim3(64), 0, stream>>>(wrec, w127, wfq);

  for (int c = 0; c < 4; ++c) {
    const size_t xoff = (size_t)c * 512 * 64 * 256;
    gemm_gx<<<dim3(256, 8), dim3(256), 0, stream>>>(x + xoff, w_in, bias, gxb);
    rnn_scan<<<dim3(16), dim3(256), LDS_TOTAL, stream>>>(
        wfq, scbuf, gxb, out + xoff, hstate, cstate, (c == 0) ? 1 : 0);
  }
}

// Round 14
// 2269.066 us; speedup vs baseline: 2.7829x; 1.1193x over previous
//
#include <hip/hip_runtime.h>
#include <cstdint>
#include <cstddef>

typedef __attribute__((ext_vector_type(8))) short short8;
typedef __attribute__((ext_vector_type(4))) float f32x4;
typedef __attribute__((ext_vector_type(4))) unsigned int u32x4;
typedef __attribute__((ext_vector_type(4))) int i32x4;

#define NEG_LOG2E -1.44269504088896340736f
#define MFMA_BF16 __builtin_amdgcn_mfma_f32_16x16x32_bf16
#define MFMA_I8 __builtin_amdgcn_mfma_i32_16x16x64_i8

// ---- helpers -------------------------------------------------------------
static __device__ __forceinline__ unsigned int cvt_pk_bf16(float lo, float hi) {
  unsigned int r;
  asm("v_cvt_pk_bf16_f32 %0, %1, %2" : "=v"(r) : "v"(lo), "v"(hi));
  return r;
}
// xs is pre-scaled by -log2(e): returns sigmoid(x_true)
static __device__ __forceinline__ float sigmoid_scaled(float xs) {
  return __builtin_amdgcn_rcpf(1.0f + __builtin_amdgcn_exp2f(xs));
}

// ===========================================================================
// Kernel 0: per-output-column scales.  Column j (0..1023) of w' = w*NEG_LOG2E:
// s_j = max_k |w'[j,k]|.  scbuf[j] = s_j/(127*127) (EPI dequant multiplier,
// folds h's 1/127), w127[j] = 127/s_j (quantizer multiplier).
// ===========================================================================
__global__ void wscale_setup(const float* __restrict__ w_rec,
                             float* __restrict__ scbuf,
                             float* __restrict__ w127) {
  const int j = blockIdx.x * 64 + threadIdx.x;  // 0..1023
  const float* row = w_rec + (size_t)j * 256;
  float m = 0.f;
  for (int k = 0; k < 256; ++k) m = fmaxf(m, fabsf(row[k]));
  float s = fmaxf(m * 1.44269504088896f, 1e-30f);
  scbuf[j] = s / 16129.0f;
  w127[j] = 127.0f / s;
}

// ===========================================================================
// Kernel 1: quantize w_rec -> i8 fragment buffer for mfma_i32_16x16x64_i8.
// 256 slots of 1 KB; slot f = w4*64 + q, q = chain*4 + kt (chain = jidx*4+g,
// kt = K-tile of 64).  jts(w4) = {2w4, 2w4+1, 2w4+8, 2w4+9}; ct = jt + 16g.
// Lane l, dwords d0..3, bytes e: q_w[col = ct*16 + (l&15)]
//                                   [k = kt*64 + (l>>4)*16 + 4d + e]
// (r12-verified layout; rnn wave w=0..7 consumes the contiguous 32-slot
//  block f in [w*32, (w+1)*32) = old-wave w>>1, jidx pair (w&1)*2..+1.)
// ===========================================================================
__global__ void wfrag_setup_i8(const float* __restrict__ w_rec,
                               const float* __restrict__ w127,
                               unsigned int* __restrict__ wfq) {
  const int f = blockIdx.x;   // 0..255
  const int l = threadIdx.x;  // 0..63
  const int w = f >> 6, q = f & 63;
  const int chain = q >> 2, kt = q & 3;
  const int jidx = chain >> 2, g = chain & 3;
  const int jt = (jidx < 2) ? (2 * w + jidx) : (2 * w + 8 + (jidx - 2));
  const int ct = jt + 16 * g;
  const int j = ct * 16 + (l & 15);
  const float r = w127[j];
  const float* src = w_rec + (size_t)j * 256 + kt * 64 + (l >> 4) * 16;
  u32x4 ov;
#pragma unroll
  for (int d = 0; d < 4; ++d) {
    unsigned int word = 0;
#pragma unroll
    for (int e = 0; e < 4; ++e) {
      int qi = (int)rintf(src[4 * d + e] * NEG_LOG2E * r);
      qi = qi > 127 ? 127 : (qi < -127 ? -127 : qi);
      word |= ((unsigned int)(qi & 255)) << (8 * e);
    }
    ov[d] = word;
  }
  *(u32x4*)(wfq + (size_t)f * 256 + (size_t)l * 4) = ov;
}

// ===========================================================================
// Kernel 2: gx = (x @ w_in^T + b) * -log2(e), bf16-packed in the layout the
// RNN consumes (r1-verified, unchanged).
// ===========================================================================
static __device__ __forceinline__ short8 ldcvt8(const float* p) {
  f32x4 v0 = *(const f32x4*)p;
  f32x4 v1 = *(const f32x4*)(p + 4);
  u32x4 u;
  u[0] = cvt_pk_bf16(v0[0], v0[1]);
  u[1] = cvt_pk_bf16(v0[2], v0[3]);
  u[2] = cvt_pk_bf16(v1[0], v1[1]);
  u[3] = cvt_pk_bf16(v1[2], v1[3]);
  return __builtin_bit_cast(short8, u);
}

__global__ __launch_bounds__(256) void gemm_gx(const float* __restrict__ x,
                                               const float* __restrict__ w_in,
                                               const float* __restrict__ bias,
                                               unsigned int* __restrict__ gx) {
  const int l = threadIdx.x & 63, wid = threadIdx.x >> 6;
  const int mq = wid >> 1, nq = wid & 1;
  const int mbase = blockIdx.x * 128 + mq * 64;
  const int nbase = blockIdx.y * 128 + nq * 64;
  const int lr = l & 15;
  const int lk = (l >> 4) * 8;

  f32x4 acc[4][4] = {};
#pragma unroll
  for (int kt = 0; kt < 8; ++kt) {
    const int k0 = kt * 32 + lk;
    short8 af[4], bf[4];
#pragma unroll
    for (int mt = 0; mt < 4; ++mt)
      af[mt] = ldcvt8(x + (size_t)(mbase + mt * 16 + lr) * 256 + k0);
#pragma unroll
    for (int nt = 0; nt < 4; ++nt)
      bf[nt] = ldcvt8(w_in + (size_t)(nbase + nt * 16 + lr) * 256 + k0);
#pragma unroll
    for (int mt = 0; mt < 4; ++mt)
#pragma unroll
      for (int nt = 0; nt < 4; ++nt)
        acc[mt][nt] = MFMA_BF16(af[mt], bf[nt], acc[mt][nt], 0, 0, 0);
  }

  float bv[4];
#pragma unroll
  for (int nt = 0; nt < 4; ++nt) bv[nt] = bias[nbase + nt * 16 + lr];

#pragma unroll
  for (int mt = 0; mt < 4; ++mt) {
    const int m0 = mbase + mt * 16;
    const int tt = m0 >> 6;
    const int bg = ((m0 & 63) >> 2) + (l >> 4);
#pragma unroll
    for (int ntp = 0; ntp < 2; ++ntp) {
      const int p = (nbase >> 5) + ntp;
#pragma unroll
      for (int r = 0; r < 4; ++r) {
        float e0 = (acc[mt][ntp * 2 + 0][r] + bv[ntp * 2 + 0]) * NEG_LOG2E;
        float e1 = (acc[mt][ntp * 2 + 1][r] + bv[ntp * 2 + 1]) * NEG_LOG2E;
        gx[(((size_t)tt * 16 + bg) * 32 + p) * 64 + (r * 16 + lr)] =
            cvt_pk_bf16(e0, e1);
      }
    }
  }
}

// ===========================================================================
// Kernel 3: scan, NOW 8 waves/block = 2 waves/SIMD.  r13's counters showed
// MFMA (~1000 cyc) and EPI VALU (~1030 cyc) nearly disjoint in one wave's
// in-order stream; two waves per SIMD let the CU co-schedule one wave's
// MFMAs with the other's VALU (m114).  Wave w = old-wave w4=w>>1, column
// half = w&1: owns coltiles jt = 2w4 + 8*half + jx (jx=0,1), 32 MFMAs/step,
// 32 i8 weight frags = 128 AGPRs + ~70 arch VGPRs (fits 256 @ 2 waves/SIMD;
// the r9/r10 bf16 overflow is gone).  All-intrinsic; h i8 ping-pong in LDS;
// one raw s_barrier/step (LDS-only drain).
// ===========================================================================
#define HB8_ROW 272                      // 256B h-row + 16B pad
#define HB8_SZ (4 * HB8_ROW)             // 1088
#define LDS_TOTAL (2 * HB8_SZ)           // 2176

#define LD4A(i)                                                         \
  asm volatile("global_load_dwordx4 %0, %4, off\n\t"                    \
               "global_load_dwordx4 %1, %4, off offset:1024\n\t"        \
               "global_load_dwordx4 %2, %4, off offset:2048\n\t"        \
               "global_load_dwordx4 %3, %4, off offset:3072"            \
               : "=&a"(wa[4 * (i)]), "=&a"(wa[4 * (i) + 1]),            \
                 "=&a"(wa[4 * (i) + 2]), "=&a"(wa[4 * (i) + 3])         \
               : "v"(pA + 4096 * (i)))

__global__ __launch_bounds__(512, 2) void rnn_scan(
    const unsigned int* __restrict__ wfq, const float* __restrict__ scbuf,
    const unsigned int* __restrict__ gx, float* __restrict__ out,
    float* __restrict__ hstate, float* __restrict__ cstate, int first) {
  extern __shared__ char lds[];
  char* hb0 = lds;
  char* hb1 = lds + HB8_SZ;

  const int l = threadIdx.x & 63;
  const int w = threadIdx.x >> 6;   // 0..7
  const int w4 = w >> 1;            // old 4-wave index 0..3
  const int half = w & 1;           // 0: jidx{0,1}, 1: jidx{2,3}
  const int bg = blockIdx.x;        // 0..15 -> batches 4bg..4bg+3
  const int bloc = l >> 4;          // local batch 0..3
  const int col = l & 15;
  const int jtl[2] = {2 * w4 + 8 * half, 2 * w4 + 8 * half + 1};

  // ---- 32 weight frags -> AGPR (128 regs); contiguous 32KB region --------
  i32x4 wa[32];
  {
    const char* pA = (const char*)wfq + (size_t)w * 32768 + (size_t)l * 16;
    LD4A(0); LD4A(1); LD4A(2); LD4A(3);
    LD4A(4); LD4A(5); LD4A(6); LD4A(7);
    asm volatile("s_waitcnt vmcnt(0)" ::: "memory");
  }
  // ---- per-column dequant scales (8 per thread) --------------------------
  float scv[8];
#pragma unroll
  for (int jx = 0; jx < 2; ++jx)
#pragma unroll
    for (int g = 0; g < 4; ++g)
      scv[jx * 4 + g] = scbuf[(jtl[jx] + 16 * g) * 16 + col];

  // ---- h / c init ---------------------------------------------------------
  float carr[2];
  if (first) {
    for (int i = threadIdx.x; i < (2 * HB8_SZ) / 4; i += 512)
      ((unsigned int*)hb0)[i] = 0u;
    carr[0] = 0.0f; carr[1] = 0.0f;
  } else {
#pragma unroll
    for (int jx = 0; jx < 2; ++jx) {
      const int jt = jtl[jx];
      const size_t idx = (size_t)(bg * 4 + bloc) * 256 + jt * 16 + col;
      carr[jx] = cstate[idx];
      const int qi = (int)rintf(hstate[idx] * 127.f);
      *(char*)(hb0 + bloc * HB8_ROW + jt * 16 + col) = (char)qi;
    }
  }

  const i32x4 kZero = {0, 0, 0, 0};  // hoisted zero-C operand

  // ---- prefetch gx(t=0): 4 dwords, ct-pair p = w4 + 4*half + 8g ----------
  unsigned int gxA[4], gxB[4];
  {
    const unsigned int* g0 = gx + (size_t)bg * 2048 + l;
#pragma unroll
    for (int g = 0; g < 4; ++g) gxA[g] = g0[(w4 + 4 * half + 8 * g) * 64];
  }
  __syncthreads();

  float* outp = out + (size_t)(bg * 4 + bloc) * 256 + col;
  const int aoff = ((l & 15) >> 2) * HB8_ROW + (l >> 4) * 16;  // A-frag read
  const int hwoff = bloc * HB8_ROW;

  auto STEP = [&](int t, char* hbR, char* hbW, unsigned int(&gxC)[4],
                  unsigned int(&gxN)[4]) {
    // next-step gx prefetch (stays in flight across the raw barrier)
    const int tn = (t + 1 < 512) ? (t + 1) : 511;
    const unsigned int* gn = gx + (size_t)tn * 32768 + (size_t)bg * 2048 + l;
#pragma unroll
    for (int g = 0; g < 4; ++g) gxN[g] = gn[(w4 + 4 * half + 8 * g) * 64];

    // A-frags (i8 h): 4 x ds_read_b128 covers K=256
    const char* hrd = hbR + aoff;
    i32x4 afv[4];
#pragma unroll
    for (int kt = 0; kt < 4; ++kt)
      afv[kt] = *(const i32x4*)(hrd + kt * 64);

    // epilogue: dequant -> gates -> c,h update -> global out + LDS i8 h
    auto EPI = [&](int jx, int s0, int s1, int s2, int s3) {
      const int jt = jtl[jx];
      const bool hi = (jx & 1) != 0;  // jt parity == jx parity
      const float g0f = hi ? __uint_as_float(gxC[0] & 0xffff0000u)
                           : __uint_as_float(gxC[0] << 16);
      const float g1f = hi ? __uint_as_float(gxC[1] & 0xffff0000u)
                           : __uint_as_float(gxC[1] << 16);
      const float g2f = hi ? __uint_as_float(gxC[2] & 0xffff0000u)
                           : __uint_as_float(gxC[2] << 16);
      const float g3f = hi ? __uint_as_float(gxC[3] & 0xffff0000u)
                           : __uint_as_float(gxC[3] << 16);
      const float gi = sigmoid_scaled(fmaf((float)s0, scv[jx * 4 + 0], g0f));
      const float go = sigmoid_scaled(fmaf((float)s1, scv[jx * 4 + 1], g1f));
      const float gz = sigmoid_scaled(fmaf((float)s2, scv[jx * 4 + 2], g2f));
      const float gf = sigmoid_scaled(fmaf((float)s3, scv[jx * 4 + 3], g3f));
      carr[jx] = gf * carr[jx] + (gz - gi);
      const float hs = sigmoid_scaled(carr[jx] * NEG_LOG2E);
      const float hn = hs - go;
      outp[(size_t)t * 16384 + jt * 16] = hn;
      const int qh = (int)rintf(hn * 127.f);
      *(char*)(hbW + hwoff + jt * 16 + col) = (char)qh;
    };

    // ---- 8 chains (2 coltiles x 4 gates), intrinsic MFMAs ----
#pragma unroll
    for (int jx = 0; jx < 2; ++jx) {
      const int cb = jx * 16;  // wa slot: jx*16 + g*4 + kt
      i32x4 d0 = MFMA_I8(afv[0], wa[cb + 0], kZero, 0, 0, 0);
      i32x4 d1 = MFMA_I8(afv[0], wa[cb + 4], kZero, 0, 0, 0);
      i32x4 d2 = MFMA_I8(afv[0], wa[cb + 8], kZero, 0, 0, 0);
      i32x4 d3 = MFMA_I8(afv[0], wa[cb + 12], kZero, 0, 0, 0);
#pragma unroll
      for (int kt = 1; kt < 4; ++kt) {
        d0 = MFMA_I8(afv[kt], wa[cb + kt], d0, 0, 0, 0);
        d1 = MFMA_I8(afv[kt], wa[cb + 4 + kt], d1, 0, 0, 0);
        d2 = MFMA_I8(afv[kt], wa[cb + 8 + kt], d2, 0, 0, 0);
        d3 = MFMA_I8(afv[kt], wa[cb + 12 + kt], d3, 0, 0, 0);
      }
      EPI(jx, d0[0], d1[0], d2[0], d3[0]);
    }

    // raw barrier: LDS-only drain (no "memory" clobber -> no vmcnt(0));
    // gx prefetch loads and out stores stay in flight across the barrier.
    __builtin_amdgcn_sched_barrier(0);
    asm volatile("s_waitcnt lgkmcnt(0)");
    __builtin_amdgcn_s_barrier();
    __builtin_amdgcn_sched_barrier(0);
  };

  for (int tt = 0; tt < 256; ++tt) {
    STEP(2 * tt, hb0, hb1, gxA, gxB);
    STEP(2 * tt + 1, hb1, hb0, gxB, gxA);
  }

  // ---- save state (h via i8 roundtrip == in-chunk path) -------------------
#pragma unroll
  for (int jx = 0; jx < 2; ++jx) {
    const int jt = jtl[jx];
    const size_t idx = (size_t)(bg * 4 + bloc) * 256 + jt * 16 + col;
    const signed char qv =
        *(const signed char*)(hb0 + hwoff + jt * 16 + col);
    hstate[idx] = (float)qv / 127.f;
    cstate[idx] = carr[jx];
  }
}

// ===========================================================================
// Host launcher.  ws layout:
//   [0,256K)        wfq i8 frags
//   [256K,260K)     scbuf (1024 f32)
//   [260K,264K)     w127 (1024 f32)
//   [512K,576K)     hstate fp32 [64][256]
//   [576K,640K)     cstate fp32 [64][256]
//   [1M, 1M+64M)    gx chunk (512 steps, bf16-packed dwords)
// ===========================================================================
extern "C" void kernel_launch(void* const* d_in, const int* in_sizes, int n_in,
                              void* d_out, int out_size, void* d_ws,
                              size_t ws_size, hipStream_t stream) {
  const float* x = (const float*)d_in[0];     // [2048][64][256]
  const float* w_in = (const float*)d_in[1];  // [1024][256]
  const float* bias = (const float*)d_in[2];  // [1024]
  const float* wrec = (const float*)d_in[3];  // [1024][256]
  float* out = (float*)d_out;                 // [2048][64][256]
  char* ws = (char*)d_ws;

  unsigned int* wfq = (unsigned int*)ws;
  float* scbuf = (float*)(ws + (256 << 10));
  float* w127 = (float*)(ws + (260 << 10));
  float* hstate = (float*)(ws + (512 << 10));
  float* cstate = (float*)(ws + (576 << 10));
  unsigned int* gxb = (unsigned int*)(ws + (1 << 20));

  (void)in_sizes; (void)n_in; (void)out_size; (void)ws_size;

  wscale_setup<<<dim3(16), dim3(64), 0, stream>>>(wrec, scbuf, w127);
  wfrag_setup_i8<<<dim3(256), dim3(64), 0, stream>>>(wrec, w127, wfq);

  for (int c = 0; c < 4; ++c) {
    const size_t xoff = (size_t)c * 512 * 64 * 256;
    gemm_gx<<<dim3(256, 8), dim3(256), 0, stream>>>(x + xoff, w_in, bias, gxb);
    rnn_scan<<<dim3(16), dim3(512), LDS_TOTAL, stream>>>(
        wfq, scbuf, gxb, out + xoff, hstate, cstate, (c == 0) ? 1 : 0);
  }
}

// Round 15
// 2193.421 us; speedup vs baseline: 2.8789x; 1.0345x over previous
//
#include <hip/hip_runtime.h>
#include <cstdint>
#include <cstddef>

typedef __attribute__((ext_vector_type(8))) short short8;
typedef __attribute__((ext_vector_type(4))) float f32x4;
typedef __attribute__((ext_vector_type(4))) unsigned int u32x4;
typedef __attribute__((ext_vector_type(4))) int i32x4;

#define NEG_LOG2E -1.44269504088896340736f
#define MFMA_BF16 __builtin_amdgcn_mfma_f32_16x16x32_bf16
#define MFMA_I8 __builtin_amdgcn_mfma_i32_16x16x64_i8

// ---- helpers -------------------------------------------------------------
static __device__ __forceinline__ unsigned int cvt_pk_bf16(float lo, float hi) {
  unsigned int r;
  asm("v_cvt_pk_bf16_f32 %0, %1, %2" : "=v"(r) : "v"(lo), "v"(hi));
  return r;
}
// xs is pre-scaled by -log2(e): returns sigmoid(x_true)
static __device__ __forceinline__ float sigmoid_scaled(float xs) {
  return __builtin_amdgcn_rcpf(1.0f + __builtin_amdgcn_exp2f(xs));
}

// ===========================================================================
// Kernel 0: per-output-column scales.  Column j (0..1023) of w' = w*NEG_LOG2E:
// s_j = max_k |w'[j,k]|.  scbuf[j] = s_j/(127*127) (EPI dequant multiplier,
// folds h's 1/127), w127[j] = 127/s_j (quantizer multiplier).
// ===========================================================================
__global__ void wscale_setup(const float* __restrict__ w_rec,
                             float* __restrict__ scbuf,
                             float* __restrict__ w127) {
  const int j = blockIdx.x * 64 + threadIdx.x;  // 0..1023
  const float* row = w_rec + (size_t)j * 256;
  float m = 0.f;
  for (int k = 0; k < 256; ++k) m = fmaxf(m, fabsf(row[k]));
  float s = fmaxf(m * 1.44269504088896f, 1e-30f);
  scbuf[j] = s / 16129.0f;
  w127[j] = 127.0f / s;
}

// ===========================================================================
// Kernel 1: quantize w_rec -> i8 fragment buffer for mfma_i32_16x16x64_i8.
// 256 slots of 1 KB; slot f = w4*64 + q, q = chain*4 + kt (chain = jidx*4+g,
// kt = K-tile of 64).  jts(w4) = {2w4, 2w4+1, 2w4+8, 2w4+9}; ct = jt + 16g.
// Lane l, dwords d0..3, bytes e: q_w[col = ct*16 + (l&15)]
//                                   [k = kt*64 + (l>>4)*16 + 4d + e]
// (r12-verified layout.  Coltile jt's 16 slots start at
//  f_base(jt) = (jt<8) ? (jt>>1)*64+(jt&1)*16 : ((jt-8)>>1)*64+(2+(jt&1))*16.)
// ===========================================================================
__global__ void wfrag_setup_i8(const float* __restrict__ w_rec,
                               const float* __restrict__ w127,
                               unsigned int* __restrict__ wfq) {
  const int f = blockIdx.x;   // 0..255
  const int l = threadIdx.x;  // 0..63
  const int w = f >> 6, q = f & 63;
  const int chain = q >> 2, kt = q & 3;
  const int jidx = chain >> 2, g = chain & 3;
  const int jt = (jidx < 2) ? (2 * w + jidx) : (2 * w + 8 + (jidx - 2));
  const int ct = jt + 16 * g;
  const int j = ct * 16 + (l & 15);
  const float r = w127[j];
  const float* src = w_rec + (size_t)j * 256 + kt * 64 + (l >> 4) * 16;
  u32x4 ov;
#pragma unroll
  for (int d = 0; d < 4; ++d) {
    unsigned int word = 0;
#pragma unroll
    for (int e = 0; e < 4; ++e) {
      int qi = (int)rintf(src[4 * d + e] * NEG_LOG2E * r);
      qi = qi > 127 ? 127 : (qi < -127 ? -127 : qi);
      word |= ((unsigned int)(qi & 255)) << (8 * e);
    }
    ov[d] = word;
  }
  *(u32x4*)(wfq + (size_t)f * 256 + (size_t)l * 4) = ov;
}

// ===========================================================================
// Kernel 2: gx = (x @ w_in^T + b) * -log2(e), bf16-packed in the layout the
// RNN consumes (r1-verified, unchanged).
// ===========================================================================
static __device__ __forceinline__ short8 ldcvt8(const float* p) {
  f32x4 v0 = *(const f32x4*)p;
  f32x4 v1 = *(const f32x4*)(p + 4);
  u32x4 u;
  u[0] = cvt_pk_bf16(v0[0], v0[1]);
  u[1] = cvt_pk_bf16(v0[2], v0[3]);
  u[2] = cvt_pk_bf16(v1[0], v1[1]);
  u[3] = cvt_pk_bf16(v1[2], v1[3]);
  return __builtin_bit_cast(short8, u);
}

__global__ __launch_bounds__(256) void gemm_gx(const float* __restrict__ x,
                                               const float* __restrict__ w_in,
                                               const float* __restrict__ bias,
                                               unsigned int* __restrict__ gx) {
  const int l = threadIdx.x & 63, wid = threadIdx.x >> 6;
  const int mq = wid >> 1, nq = wid & 1;
  const int mbase = blockIdx.x * 128 + mq * 64;
  const int nbase = blockIdx.y * 128 + nq * 64;
  const int lr = l & 15;
  const int lk = (l >> 4) * 8;

  f32x4 acc[4][4] = {};
#pragma unroll
  for (int kt = 0; kt < 8; ++kt) {
    const int k0 = kt * 32 + lk;
    short8 af[4], bf[4];
#pragma unroll
    for (int mt = 0; mt < 4; ++mt)
      af[mt] = ldcvt8(x + (size_t)(mbase + mt * 16 + lr) * 256 + k0);
#pragma unroll
    for (int nt = 0; nt < 4; ++nt)
      bf[nt] = ldcvt8(w_in + (size_t)(nbase + nt * 16 + lr) * 256 + k0);
#pragma unroll
    for (int mt = 0; mt < 4; ++mt)
#pragma unroll
      for (int nt = 0; nt < 4; ++nt)
        acc[mt][nt] = MFMA_BF16(af[mt], bf[nt], acc[mt][nt], 0, 0, 0);
  }

  float bv[4];
#pragma unroll
  for (int nt = 0; nt < 4; ++nt) bv[nt] = bias[nbase + nt * 16 + lr];

#pragma unroll
  for (int mt = 0; mt < 4; ++mt) {
    const int m0 = mbase + mt * 16;
    const int tt = m0 >> 6;
    const int bg = ((m0 & 63) >> 2) + (l >> 4);
#pragma unroll
    for (int ntp = 0; ntp < 2; ++ntp) {
      const int p = (nbase >> 5) + ntp;
#pragma unroll
      for (int r = 0; r < 4; ++r) {
        float e0 = (acc[mt][ntp * 2 + 0][r] + bv[ntp * 2 + 0]) * NEG_LOG2E;
        float e1 = (acc[mt][ntp * 2 + 1][r] + bv[ntp * 2 + 1]) * NEG_LOG2E;
        gx[(((size_t)tt * 16 + bg) * 32 + p) * 64 + (r * 16 + lr)] =
            cvt_pk_bf16(e0, e1);
      }
    }
  }
}

// ===========================================================================
// Kernel 3: scan, NOW 16 waves/block = 4 waves/SIMD.  r14's counters showed
// ~1000 cyc MFMA + ~900 cyc dep-stall per step with only partial 2-wave
// cover; 4 independent wave streams per SIMD fill each other's stalls.
// Wave w owns coltile jt = w: 16 i8 weight frags = 64 AGPRs, 16 MFMAs +
// 1 EPI per step.  Per-wave budget must fit 128 unified regs (16-wave block
// fully resident) -- hence one coltile/wave and minimal live state.
// gx dword p = (jt>>1) + 8g, hi half = jt&1 (even/odd waves share dwords).
// h i8 ping-pong in LDS; one raw s_barrier/step (LDS-only drain).
// ===========================================================================
#define HB8_ROW 272                      // 256B h-row + 16B pad
#define HB8_SZ (4 * HB8_ROW)             // 1088
#define LDS_TOTAL (2 * HB8_SZ)           // 2176

#define LD4A(i)                                                         \
  asm volatile("global_load_dwordx4 %0, %4, off\n\t"                    \
               "global_load_dwordx4 %1, %4, off offset:1024\n\t"        \
               "global_load_dwordx4 %2, %4, off offset:2048\n\t"        \
               "global_load_dwordx4 %3, %4, off offset:3072"            \
               : "=&a"(wa[4 * (i)]), "=&a"(wa[4 * (i) + 1]),            \
                 "=&a"(wa[4 * (i) + 2]), "=&a"(wa[4 * (i) + 3])         \
               : "v"(pA + 4096 * (i)))

__global__ __launch_bounds__(1024) void rnn_scan(
    const unsigned int* __restrict__ wfq, const float* __restrict__ scbuf,
    const unsigned int* __restrict__ gx, float* __restrict__ out,
    float* __restrict__ hstate, float* __restrict__ cstate, int first) {
  extern __shared__ char lds[];
  char* hb0 = lds;
  char* hb1 = lds + HB8_SZ;

  const int l = threadIdx.x & 63;
  const int w = threadIdx.x >> 6;   // 0..15 -> coltile jt = w
  const int bg = blockIdx.x;        // 0..15 -> batches 4bg..4bg+3
  const int bloc = l >> 4;          // local batch 0..3
  const int col = l & 15;
  const int jt = w;
  const int fbase = (jt < 8) ? ((jt >> 1) * 64 + (jt & 1) * 16)
                             : (((jt - 8) >> 1) * 64 + (2 + (jt & 1)) * 16);

  // ---- 16 weight frags -> AGPR (64 regs); contiguous 16KB region ---------
  i32x4 wa[16];
  {
    const char* pA = (const char*)wfq + (size_t)fbase * 1024 + (size_t)l * 16;
    LD4A(0); LD4A(1); LD4A(2); LD4A(3);
    asm volatile("s_waitcnt vmcnt(0)" ::: "memory");
  }
  // ---- per-column dequant scales (4 per thread) --------------------------
  float scv[4];
#pragma unroll
  for (int g = 0; g < 4; ++g)
    scv[g] = scbuf[(jt + 16 * g) * 16 + col];

  // ---- h / c init ---------------------------------------------------------
  float carr;
  if (first) {
    for (int i = threadIdx.x; i < (2 * HB8_SZ) / 4; i += 1024)
      ((unsigned int*)hb0)[i] = 0u;
    carr = 0.0f;
  } else {
    const size_t idx = (size_t)(bg * 4 + bloc) * 256 + jt * 16 + col;
    carr = cstate[idx];
    const int qi = (int)rintf(hstate[idx] * 127.f);
    *(char*)(hb0 + bloc * HB8_ROW + jt * 16 + col) = (char)qi;
  }

  // ---- prefetch gx(t=0): 4 dwords, ct-pair p = (jt>>1) + 8g --------------
  unsigned int gxA[4], gxB[4];
  {
    const unsigned int* g0 = gx + (size_t)bg * 2048 + l;
#pragma unroll
    for (int g = 0; g < 4; ++g) gxA[g] = g0[((jt >> 1) + 8 * g) * 64];
  }
  __syncthreads();

  float* outp = out + (size_t)(bg * 4 + bloc) * 256 + col + jt * 16;
  const int aoff = ((l & 15) >> 2) * HB8_ROW + (l >> 4) * 16;  // A-frag read
  const int hwoff = bloc * HB8_ROW;
  const bool hi = (jt & 1) != 0;

  auto STEP = [&](int t, char* hbR, char* hbW, unsigned int(&gxC)[4],
                  unsigned int(&gxN)[4]) {
    // next-step gx prefetch (stays in flight across the raw barrier)
    const int tn = (t + 1 < 512) ? (t + 1) : 511;
    const unsigned int* gn = gx + (size_t)tn * 32768 + (size_t)bg * 2048 + l;
#pragma unroll
    for (int g = 0; g < 4; ++g) gxN[g] = gn[((jt >> 1) + 8 * g) * 64];

    // A-frags (i8 h): 4 x ds_read_b128 covers K=256
    const char* hrd = hbR + aoff;
    i32x4 afv[4];
#pragma unroll
    for (int kt = 0; kt < 4; ++kt)
      afv[kt] = *(const i32x4*)(hrd + kt * 64);

    // ---- 4 gate chains x 4 kt, intrinsic MFMAs ----
    i32x4 d0 = {0, 0, 0, 0}, d1 = d0, d2 = d0, d3 = d0;
#pragma unroll
    for (int kt = 0; kt < 4; ++kt) {
      d0 = MFMA_I8(afv[kt], wa[kt], d0, 0, 0, 0);
      d1 = MFMA_I8(afv[kt], wa[4 + kt], d1, 0, 0, 0);
      d2 = MFMA_I8(afv[kt], wa[8 + kt], d2, 0, 0, 0);
      d3 = MFMA_I8(afv[kt], wa[12 + kt], d3, 0, 0, 0);
    }

    // epilogue: dequant -> gates -> c,h update -> global out + LDS i8 h
    {
      const float g0f = hi ? __uint_as_float(gxC[0] & 0xffff0000u)
                           : __uint_as_float(gxC[0] << 16);
      const float g1f = hi ? __uint_as_float(gxC[1] & 0xffff0000u)
                           : __uint_as_float(gxC[1] << 16);
      const float g2f = hi ? __uint_as_float(gxC[2] & 0xffff0000u)
                           : __uint_as_float(gxC[2] << 16);
      const float g3f = hi ? __uint_as_float(gxC[3] & 0xffff0000u)
                           : __uint_as_float(gxC[3] << 16);
      const float gi = sigmoid_scaled(fmaf((float)d0[0], scv[0], g0f));
      const float go = sigmoid_scaled(fmaf((float)d1[0], scv[1], g1f));
      const float gz = sigmoid_scaled(fmaf((float)d2[0], scv[2], g2f));
      const float gf = sigmoid_scaled(fmaf((float)d3[0], scv[3], g3f));
      carr = gf * carr + (gz - gi);
      const float hs = sigmoid_scaled(carr * NEG_LOG2E);
      const float hn = hs - go;
      outp[(size_t)t * 16384] = hn;
      const int qh = (int)rintf(hn * 127.f);
      *(char*)(hbW + hwoff + jt * 16 + col) = (char)qh;
    }

    // raw barrier: LDS-only drain (no "memory" clobber -> no vmcnt(0));
    // gx prefetch loads and out stores stay in flight across the barrier.
    __builtin_amdgcn_sched_barrier(0);
    asm volatile("s_waitcnt lgkmcnt(0)");
    __builtin_amdgcn_s_barrier();
    __builtin_amdgcn_sched_barrier(0);
  };

  for (int tt = 0; tt < 256; ++tt) {
    STEP(2 * tt, hb0, hb1, gxA, gxB);
    STEP(2 * tt + 1, hb1, hb0, gxB, gxA);
  }

  // ---- save state (h via i8 roundtrip == in-chunk path) -------------------
  {
    const size_t idx = (size_t)(bg * 4 + bloc) * 256 + jt * 16 + col;
    const signed char qv =
        *(const signed char*)(hb0 + hwoff + jt * 16 + col);
    hstate[idx] = (float)qv / 127.f;
    cstate[idx] = carr;
  }
}

// ===========================================================================
// Host launcher.  ws layout:
//   [0,256K)        wfq i8 frags
//   [256K,260K)     scbuf (1024 f32)
//   [260K,264K)     w127 (1024 f32)
//   [512K,576K)     hstate fp32 [64][256]
//   [576K,640K)     cstate fp32 [64][256]
//   [1M, 1M+64M)    gx chunk (512 steps, bf16-packed dwords)
// ===========================================================================
extern "C" void kernel_launch(void* const* d_in, const int* in_sizes, int n_in,
                              void* d_out, int out_size, void* d_ws,
                              size_t ws_size, hipStream_t stream) {
  const float* x = (const float*)d_in[0];     // [2048][64][256]
  const float* w_in = (const float*)d_in[1];  // [1024][256]
  const float* bias = (const float*)d_in[2];  // [1024]
  const float* wrec = (const float*)d_in[3];  // [1024][256]
  float* out = (float*)d_out;                 // [2048][64][256]
  char* ws = (char*)d_ws;

  unsigned int* wfq = (unsigned int*)ws;
  float* scbuf = (float*)(ws + (256 << 10));
  float* w127 = (float*)(ws + (260 << 10));
  float* hstate = (float*)(ws + (512 << 10));
  float* cstate = (float*)(ws + (576 << 10));
  unsigned int* gxb = (unsigned int*)(ws + (1 << 20));

  (void)in_sizes; (void)n_in; (void)out_size; (void)ws_size;

  wscale_setup<<<dim3(16), dim3(64), 0, stream>>>(wrec, scbuf, w127);
  wfrag_setup_i8<<<dim3(256), dim3(64), 0, stream>>>(wrec, w127, wfq);

  for (int c = 0; c < 4; ++c) {
    const size_t xoff = (size_t)c * 512 * 64 * 256;
    gemm_gx<<<dim3(256, 8), dim3(256), 0, stream>>>(x + xoff, w_in, bias, gxb);
    rnn_scan<<<dim3(16), dim3(1024), LDS_TOTAL, stream>>>(
        wfq, scbuf, gxb, out + xoff, hstate, cstate, (c == 0) ? 1 : 0);
  }
}